// Round 1
// baseline (6452.783 us; speedup 1.0000x reference)
//
#include <hip/hip_runtime.h>
#include <math.h>

// Sizes (validated at runtime from in_sizes)
// N = 100000, E = 1600000, F_IN = H = 128, C = 40

__global__ __launch_bounds__(256) void scatter_add_kernel(
    const float4* __restrict__ xin,   // [N][32] float4 view of [N][128]
    const int* __restrict__ src,
    const int* __restrict__ dst,
    float* __restrict__ agg,          // [N][128]
    int nE, int nN)
{
    long tid = (long)blockIdx.x * blockDim.x + threadIdx.x;
    long total = (long)nE * 32;
    if (tid >= total) return;
    int e = (int)(tid >> 5);
    int c = (int)(tid & 31);
    int s = src[e], d = dst[e];
    if ((unsigned)s >= (unsigned)nN || (unsigned)d >= (unsigned)nN) return;
    float4 v = xin[(long)s * 32 + c];
    float* out = agg + (long)d * 128 + c * 4;
    atomicAdd(out + 0, v.x);
    atomicAdd(out + 1, v.y);
    atomicAdd(out + 2, v.z);
    atomicAdd(out + 3, v.w);
}

// h[i][o] = relu( sum_k agg[i][k]*W1_rel[o][k] + b1[o] + sum_k x[i][k]*W1_root[o][k] )
// block = 128 threads (o = tid), 8 nodes per block; weights in regs across node loop
__global__ __launch_bounds__(128) void linear1_relu_kernel(
    const float* __restrict__ agg,    // [N][128]
    const float* __restrict__ x,      // [N][128]
    const float* __restrict__ Wrel,   // [128][128]
    const float* __restrict__ b,      // [128]
    const float* __restrict__ Wroot,  // [128][128]
    float* __restrict__ h,            // [N][128]
    int nN)
{
    int o = threadIdx.x;          // 0..127
    int base = blockIdx.x * 8;
    float acc[8] = {0.f, 0.f, 0.f, 0.f, 0.f, 0.f, 0.f, 0.f};

    const float4* wr = (const float4*)(Wrel + (long)o * 128);
    const float4* wo = (const float4*)(Wroot + (long)o * 128);

    #pragma unroll 4
    for (int k4 = 0; k4 < 32; ++k4) {
        float4 a = wr[k4];
        float4 c2 = wo[k4];
        #pragma unroll
        for (int n = 0; n < 8; ++n) {
            const float4 av = ((const float4*)(agg + (long)(base + n) * 128))[k4];
            const float4 xv = ((const float4*)(x   + (long)(base + n) * 128))[k4];
            acc[n] += av.x * a.x + av.y * a.y + av.z * a.z + av.w * a.w;
            acc[n] += xv.x * c2.x + xv.y * c2.y + xv.z * c2.z + xv.w * c2.w;
        }
    }
    float bias = b[o];
    #pragma unroll
    for (int n = 0; n < 8; ++n) {
        int row = base + n;
        if (row < nN) h[(long)row * 128 + o] = fmaxf(acc[n] + bias, 0.f);
    }
}

// out[i][c] = log_softmax( sum_k agg2[i][k]*W2_rel[c][k] + b2[c] + sum_k h[i][k]*W2_root[c][k] )
// one wave per node; lanes 0..39 carry classes
__global__ __launch_bounds__(256) void linear2_lsm_kernel(
    const float* __restrict__ agg,    // [N][128]
    const float* __restrict__ h,      // [N][128]
    const float* __restrict__ Wrel,   // [40][128]
    const float* __restrict__ b,      // [40]
    const float* __restrict__ Wroot,  // [40][128]
    float* __restrict__ out,          // [N][40]
    int nN)
{
    int wave = threadIdx.x >> 6;           // 0..3
    int lane = threadIdx.x & 63;
    int node = blockIdx.x * 4 + wave;
    if (node >= nN) return;

    float acc;
    if (lane < 40) {
        const float4* wr = (const float4*)(Wrel + (long)lane * 128);
        const float4* wo = (const float4*)(Wroot + (long)lane * 128);
        const float4* av = (const float4*)(agg + (long)node * 128);
        const float4* hv = (const float4*)(h + (long)node * 128);
        float s = 0.f;
        #pragma unroll 8
        for (int k4 = 0; k4 < 32; ++k4) {
            float4 a = wr[k4];
            float4 c2 = wo[k4];
            float4 A = av[k4];
            float4 X = hv[k4];
            s += A.x * a.x + A.y * a.y + A.z * a.z + A.w * a.w;
            s += X.x * c2.x + X.y * c2.y + X.z * c2.z + X.w * c2.w;
        }
        acc = s + b[lane];
    } else {
        acc = -INFINITY;
    }

    // 64-lane max reduction
    float m = acc;
    #pragma unroll
    for (int off = 32; off > 0; off >>= 1) m = fmaxf(m, __shfl_xor(m, off));
    float e = (lane < 40) ? expf(acc - m) : 0.f;
    float ssum = e;
    #pragma unroll
    for (int off = 32; off > 0; off >>= 1) ssum += __shfl_xor(ssum, off);

    if (lane < 40) out[(long)node * 40 + lane] = acc - m - logf(ssum);
}

extern "C" void kernel_launch(void* const* d_in, const int* in_sizes, int n_in,
                              void* d_out, int out_size, void* d_ws, size_t ws_size,
                              hipStream_t stream)
{
    const float* x       = (const float*)d_in[0];
    const int*   ei      = (const int*)d_in[1];
    const float* W1_rel  = (const float*)d_in[2];
    const float* b1      = (const float*)d_in[3];
    const float* W1_root = (const float*)d_in[4];
    const float* W2_rel  = (const float*)d_in[5];
    const float* b2      = (const float*)d_in[6];
    const float* W2_root = (const float*)d_in[7];

    int N = in_sizes[0] / 128;
    int E = in_sizes[1] / 2;

    float* agg = (float*)d_ws;                       // [N][128]
    float* h   = agg + (size_t)N * 128;              // [N][128]

    const int* srcp = ei;
    const int* dstp = ei + E;

    size_t aggBytes = (size_t)N * 128 * sizeof(float);

    // ---- layer 1 ----
    hipMemsetAsync(agg, 0, aggBytes, stream);
    {
        long total = (long)E * 32;
        int blocks = (int)((total + 255) / 256);
        scatter_add_kernel<<<blocks, 256, 0, stream>>>(
            (const float4*)x, srcp, dstp, agg, E, N);
    }
    linear1_relu_kernel<<<(N + 7) / 8, 128, 0, stream>>>(
        agg, x, W1_rel, b1, W1_root, h, N);

    // ---- layer 2 ----
    hipMemsetAsync(agg, 0, aggBytes, stream);
    {
        long total = (long)E * 32;
        int blocks = (int)((total + 255) / 256);
        scatter_add_kernel<<<blocks, 256, 0, stream>>>(
            (const float4*)h, srcp, dstp, agg, E, N);
    }
    linear2_lsm_kernel<<<(N + 3) / 4, 256, 0, stream>>>(
        agg, h, W2_rel, b2, W2_root, (float*)d_out, N);
}

// Round 2
// 1801.352 us; speedup vs baseline: 3.5822x; 3.5822x over previous
//
#include <hip/hip_runtime.h>
#include <math.h>

// N = 100000, E = 1600000, F_IN = H = 128, C = 40

// ---------------- CSR build ----------------

__global__ __launch_bounds__(256) void hist_kernel(
    const int* __restrict__ dst, int* __restrict__ cnt, int nE, int nN)
{
    int e = blockIdx.x * blockDim.x + threadIdx.x;
    if (e >= nE) return;
    int d = dst[e];
    if ((unsigned)d < (unsigned)nN) atomicAdd(&cnt[d], 1);
}

// single block, 1024 threads: exclusive scan of cnt[0..nN) -> rowptr[0..nN],
// also writes cursor[i] = rowptr[i] for the fill pass.
__global__ __launch_bounds__(1024) void scan_kernel(
    const int* __restrict__ cnt, int* __restrict__ rowptr,
    int* __restrict__ cursor, int nN)
{
    __shared__ int sums[1024];
    int t = threadIdx.x;
    int chunk = (nN + 1023) / 1024;
    int lo = t * chunk;
    int hi = lo + chunk; if (hi > nN) hi = nN;
    if (lo > nN) lo = nN;

    int s = 0;
    for (int i = lo; i < hi; ++i) s += cnt[i];
    sums[t] = s;
    __syncthreads();
    // inclusive Hillis-Steele scan over the 1024 partial sums
    for (int off = 1; off < 1024; off <<= 1) {
        int v = (t >= off) ? sums[t - off] : 0;
        __syncthreads();
        sums[t] += v;
        __syncthreads();
    }
    int prefix = (t == 0) ? 0 : sums[t - 1];
    for (int i = lo; i < hi; ++i) {
        int c = cnt[i];
        rowptr[i] = prefix;
        cursor[i] = prefix;
        prefix += c;
    }
    if (t == 1023) rowptr[nN] = sums[1023];
}

__global__ __launch_bounds__(256) void fill_kernel(
    const int* __restrict__ src, const int* __restrict__ dst,
    int* __restrict__ cursor, int* __restrict__ sorted_src, int nE, int nN)
{
    int e = blockIdx.x * blockDim.x + threadIdx.x;
    if (e >= nE) return;
    int d = dst[e];
    if ((unsigned)d >= (unsigned)nN) return;
    int pos = atomicAdd(&cursor[d], 1);
    sorted_src[pos] = src[e];
}

// ---------------- gather aggregation (no float atomics) ----------------
// one wave per node; lane owns a float2 column (64*2 = 128 features)
__global__ __launch_bounds__(256) void aggregate_kernel(
    const float2* __restrict__ xin,       // [N][64] float2 view of [N][128]
    const int* __restrict__ rowptr,
    const int* __restrict__ sorted_src,
    float2* __restrict__ agg,             // [N][64]
    int nN)
{
    int wave = threadIdx.x >> 6;
    int lane = threadIdx.x & 63;
    int node = blockIdx.x * 4 + wave;
    if (node >= nN) return;
    int beg = rowptr[node], end = rowptr[node + 1];
    float2 acc = make_float2(0.f, 0.f);
    for (int j = beg; j < end; ++j) {
        int s = sorted_src[j];                // wave-uniform -> broadcast
        float2 v = xin[(long)s * 64 + lane];  // coalesced 512B wave read
        acc.x += v.x; acc.y += v.y;
    }
    agg[(long)node * 64 + lane] = acc;
}

// ---------------- fallback: atomic scatter (if ws too small) ----------------
__global__ __launch_bounds__(256) void scatter_add_kernel(
    const float4* __restrict__ xin, const int* __restrict__ src,
    const int* __restrict__ dst, float* __restrict__ agg, int nE, int nN)
{
    long tid = (long)blockIdx.x * blockDim.x + threadIdx.x;
    long total = (long)nE * 32;
    if (tid >= total) return;
    int e = (int)(tid >> 5);
    int c = (int)(tid & 31);
    int s = src[e], d = dst[e];
    if ((unsigned)s >= (unsigned)nN || (unsigned)d >= (unsigned)nN) return;
    float4 v = xin[(long)s * 32 + c];
    float* out = agg + (long)d * 128 + c * 4;
    atomicAdd(out + 0, v.x);
    atomicAdd(out + 1, v.y);
    atomicAdd(out + 2, v.z);
    atomicAdd(out + 3, v.w);
}

// ---------------- dense layers ----------------

__global__ __launch_bounds__(128) void linear1_relu_kernel(
    const float* __restrict__ agg, const float* __restrict__ x,
    const float* __restrict__ Wrel, const float* __restrict__ b,
    const float* __restrict__ Wroot, float* __restrict__ h, int nN)
{
    int o = threadIdx.x;          // 0..127
    int base = blockIdx.x * 8;
    float acc[8] = {0.f, 0.f, 0.f, 0.f, 0.f, 0.f, 0.f, 0.f};

    const float4* wr = (const float4*)(Wrel + (long)o * 128);
    const float4* wo = (const float4*)(Wroot + (long)o * 128);

    #pragma unroll 4
    for (int k4 = 0; k4 < 32; ++k4) {
        float4 a = wr[k4];
        float4 c2 = wo[k4];
        #pragma unroll
        for (int n = 0; n < 8; ++n) {
            const float4 av = ((const float4*)(agg + (long)(base + n) * 128))[k4];
            const float4 xv = ((const float4*)(x   + (long)(base + n) * 128))[k4];
            acc[n] += av.x * a.x + av.y * a.y + av.z * a.z + av.w * a.w;
            acc[n] += xv.x * c2.x + xv.y * c2.y + xv.z * c2.z + xv.w * c2.w;
        }
    }
    float bias = b[o];
    #pragma unroll
    for (int n = 0; n < 8; ++n) {
        int row = base + n;
        if (row < nN) h[(long)row * 128 + o] = fmaxf(acc[n] + bias, 0.f);
    }
}

__global__ __launch_bounds__(256) void linear2_lsm_kernel(
    const float* __restrict__ agg, const float* __restrict__ h,
    const float* __restrict__ Wrel, const float* __restrict__ b,
    const float* __restrict__ Wroot, float* __restrict__ out, int nN)
{
    int wave = threadIdx.x >> 6;
    int lane = threadIdx.x & 63;
    int node = blockIdx.x * 4 + wave;
    if (node >= nN) return;

    float acc;
    if (lane < 40) {
        const float4* wr = (const float4*)(Wrel + (long)lane * 128);
        const float4* wo = (const float4*)(Wroot + (long)lane * 128);
        const float4* av = (const float4*)(agg + (long)node * 128);
        const float4* hv = (const float4*)(h + (long)node * 128);
        float s = 0.f;
        #pragma unroll 8
        for (int k4 = 0; k4 < 32; ++k4) {
            float4 a = wr[k4];
            float4 c2 = wo[k4];
            float4 A = av[k4];
            float4 X = hv[k4];
            s += A.x * a.x + A.y * a.y + A.z * a.z + A.w * a.w;
            s += X.x * c2.x + X.y * c2.y + X.z * c2.z + X.w * c2.w;
        }
        acc = s + b[lane];
    } else {
        acc = -INFINITY;
    }

    float m = acc;
    #pragma unroll
    for (int off = 32; off > 0; off >>= 1) m = fmaxf(m, __shfl_xor(m, off));
    float e = (lane < 40) ? expf(acc - m) : 0.f;
    float ssum = e;
    #pragma unroll
    for (int off = 32; off > 0; off >>= 1) ssum += __shfl_xor(ssum, off);

    if (lane < 40) out[(long)node * 40 + lane] = acc - m - logf(ssum);
}

// ---------------- launch ----------------

extern "C" void kernel_launch(void* const* d_in, const int* in_sizes, int n_in,
                              void* d_out, int out_size, void* d_ws, size_t ws_size,
                              hipStream_t stream)
{
    const float* x       = (const float*)d_in[0];
    const int*   ei      = (const int*)d_in[1];
    const float* W1_rel  = (const float*)d_in[2];
    const float* b1      = (const float*)d_in[3];
    const float* W1_root = (const float*)d_in[4];
    const float* W2_rel  = (const float*)d_in[5];
    const float* b2      = (const float*)d_in[6];
    const float* W2_root = (const float*)d_in[7];

    int N = in_sizes[0] / 128;
    int E = in_sizes[1] / 2;

    const int* srcp = ei;
    const int* dstp = ei + E;

    size_t fElems = (size_t)N * 128;
    float* agg = (float*)d_ws;            // [N][128]
    float* h   = agg + fElems;            // [N][128]
    int*   rowptr     = (int*)(h + fElems);          // [N+1]
    int*   cursor     = rowptr + (N + 1);            // [N]
    int*   sorted_src = cursor + N;                  // [E]

    size_t needed = 2 * fElems * sizeof(float) + (size_t)(2 * N + 1 + E) * sizeof(int);
    bool useCSR = (ws_size >= needed);

    if (useCSR) {
        // build CSR by destination (once, reused by both layers)
        hipMemsetAsync(cursor, 0, (size_t)N * sizeof(int), stream);
        hist_kernel<<<(E + 255) / 256, 256, 0, stream>>>(dstp, cursor, E, N);
        scan_kernel<<<1, 1024, 0, stream>>>(cursor, rowptr, cursor, N);
        fill_kernel<<<(E + 255) / 256, 256, 0, stream>>>(srcp, dstp, cursor, sorted_src, E, N);

        // layer 1
        aggregate_kernel<<<(N + 3) / 4, 256, 0, stream>>>(
            (const float2*)x, rowptr, sorted_src, (float2*)agg, N);
        linear1_relu_kernel<<<(N + 7) / 8, 128, 0, stream>>>(
            agg, x, W1_rel, b1, W1_root, h, N);

        // layer 2
        aggregate_kernel<<<(N + 3) / 4, 256, 0, stream>>>(
            (const float2*)h, rowptr, sorted_src, (float2*)agg, N);
        linear2_lsm_kernel<<<(N + 3) / 4, 256, 0, stream>>>(
            agg, h, W2_rel, b2, W2_root, (float*)d_out, N);
    } else {
        size_t aggBytes = fElems * sizeof(float);
        long total = (long)E * 32;
        int blocks = (int)((total + 255) / 256);

        hipMemsetAsync(agg, 0, aggBytes, stream);
        scatter_add_kernel<<<blocks, 256, 0, stream>>>((const float4*)x, srcp, dstp, agg, E, N);
        linear1_relu_kernel<<<(N + 7) / 8, 128, 0, stream>>>(agg, x, W1_rel, b1, W1_root, h, N);

        hipMemsetAsync(agg, 0, aggBytes, stream);
        scatter_add_kernel<<<blocks, 256, 0, stream>>>((const float4*)h, srcp, dstp, agg, E, N);
        linear2_lsm_kernel<<<(N + 3) / 4, 256, 0, stream>>>(agg, h, W2_rel, b2, W2_root, (float*)d_out, N);
    }
}

// Round 3
// 623.008 us; speedup vs baseline: 10.3575x; 2.8914x over previous
//
#include <hip/hip_runtime.h>
#include <hip/hip_bf16.h>
#include <math.h>

// N = 100000, E = 1600000, F_IN = H = 128, C = 40
typedef __bf16 bf16x8 __attribute__((ext_vector_type(8)));
typedef float f32x4 __attribute__((ext_vector_type(4)));
typedef unsigned int uint32;
typedef unsigned short ushort16;

// ---------------- CSR build ----------------

__global__ __launch_bounds__(256) void hist_kernel(
    const int* __restrict__ dst, int* __restrict__ cnt, int nE, int nN)
{
    int e = blockIdx.x * blockDim.x + threadIdx.x;
    if (e >= nE) return;
    int d = dst[e];
    if ((unsigned)d < (unsigned)nN) atomicAdd(&cnt[d], 1);
}

__global__ __launch_bounds__(1024) void scan_kernel(
    const int* __restrict__ cnt, int* __restrict__ rowptr,
    int* __restrict__ cursor, int nN)
{
    __shared__ int sums[1024];
    int t = threadIdx.x;
    int chunk = (nN + 1023) / 1024;
    int lo = t * chunk;
    int hi = lo + chunk; if (hi > nN) hi = nN;
    if (lo > nN) lo = nN;

    int s = 0;
    for (int i = lo; i < hi; ++i) s += cnt[i];
    sums[t] = s;
    __syncthreads();
    for (int off = 1; off < 1024; off <<= 1) {
        int v = (t >= off) ? sums[t - off] : 0;
        __syncthreads();
        sums[t] += v;
        __syncthreads();
    }
    int prefix = (t == 0) ? 0 : sums[t - 1];
    for (int i = lo; i < hi; ++i) {
        int c = cnt[i];
        rowptr[i] = prefix;
        cursor[i] = prefix;
        prefix += c;
    }
    if (t == 1023) rowptr[nN] = sums[1023];
}

__global__ __launch_bounds__(256) void fill_kernel(
    const int* __restrict__ src, const int* __restrict__ dst,
    int* __restrict__ cursor, int* __restrict__ sorted_src, int nE, int nN)
{
    int e = blockIdx.x * blockDim.x + threadIdx.x;
    if (e >= nE) return;
    int d = dst[e];
    if ((unsigned)d >= (unsigned)nN) return;
    int pos = atomicAdd(&cursor[d], 1);
    sorted_src[pos] = src[e];
}

// ---------------- conversions ----------------

__global__ __launch_bounds__(256) void cvt_bf16_kernel(
    const float4* __restrict__ in, ushort4* __restrict__ out, int n4)
{
    int i = blockIdx.x * blockDim.x + threadIdx.x;
    int stride = gridDim.x * blockDim.x;
    for (; i < n4; i += stride) {
        float4 v = in[i];
        ushort4 o;
        o.x = __builtin_bit_cast(unsigned short, __float2bfloat16(v.x));
        o.y = __builtin_bit_cast(unsigned short, __float2bfloat16(v.y));
        o.z = __builtin_bit_cast(unsigned short, __float2bfloat16(v.z));
        o.w = __builtin_bit_cast(unsigned short, __float2bfloat16(v.w));
        out[i] = o;
    }
}

// W1relB[128*128], W1rootB[128*128], W2cat[48*256] (rows>=40 zero)
__global__ __launch_bounds__(256) void prep_weights_kernel(
    const float* __restrict__ W1_rel, const float* __restrict__ W1_root,
    const float* __restrict__ W2_rel, const float* __restrict__ W2_root,
    unsigned short* __restrict__ W1relB, unsigned short* __restrict__ W1rootB,
    unsigned short* __restrict__ W2cat)
{
    int i = blockIdx.x * 256 + threadIdx.x;
    if (i < 16384) {
        W1relB[i] = __builtin_bit_cast(unsigned short, __float2bfloat16(W1_rel[i]));
    } else if (i < 32768) {
        int j = i - 16384;
        W1rootB[j] = __builtin_bit_cast(unsigned short, __float2bfloat16(W1_root[j]));
    } else if (i < 32768 + 12288) {
        int j = i - 32768;
        int o = j >> 8, k = j & 255;
        float v = 0.f;
        if (o < 40) v = (k < 128) ? W2_rel[o * 128 + k] : W2_root[o * 128 + (k - 128)];
        W2cat[j] = __builtin_bit_cast(unsigned short, __float2bfloat16(v));
    }
}

// ---------------- gather aggregation (bf16 in, bf16 out, f32 accum) ----------------
// one wave per node; lane owns 2 features packed in a uint32
__global__ __launch_bounds__(256) void aggregate_bf16_kernel(
    const uint32* __restrict__ xin,       // [N][64] (2 bf16 / uint)
    const int* __restrict__ rowptr,
    const int* __restrict__ sorted_src,
    uint32* __restrict__ aggout,          // [N][64]
    int nN)
{
    int wave = threadIdx.x >> 6;
    int lane = threadIdx.x & 63;
    int node = blockIdx.x * 4 + wave;
    if (node >= nN) return;
    int beg = rowptr[node], end = rowptr[node + 1];
    float a0 = 0.f, a1 = 0.f, b0 = 0.f, b1 = 0.f;
    int j = beg;
    for (; j + 4 <= end; j += 4) {
        int s0 = sorted_src[j], s1 = sorted_src[j + 1];
        int s2 = sorted_src[j + 2], s3 = sorted_src[j + 3];
        uint32 u0 = xin[(size_t)s0 * 64 + lane];
        uint32 u1 = xin[(size_t)s1 * 64 + lane];
        uint32 u2 = xin[(size_t)s2 * 64 + lane];
        uint32 u3 = xin[(size_t)s3 * 64 + lane];
        a0 += __uint_as_float(u0 << 16);
        a1 += __uint_as_float(u0 & 0xffff0000u);
        b0 += __uint_as_float(u1 << 16);
        b1 += __uint_as_float(u1 & 0xffff0000u);
        a0 += __uint_as_float(u2 << 16);
        a1 += __uint_as_float(u2 & 0xffff0000u);
        b0 += __uint_as_float(u3 << 16);
        b1 += __uint_as_float(u3 & 0xffff0000u);
    }
    for (; j < end; ++j) {
        uint32 u = xin[(size_t)sorted_src[j] * 64 + lane];
        a0 += __uint_as_float(u << 16);
        a1 += __uint_as_float(u & 0xffff0000u);
    }
    a0 += b0; a1 += b1;
    uint32 lo = __builtin_bit_cast(unsigned short, __float2bfloat16(a0));
    uint32 hi = __builtin_bit_cast(unsigned short, __float2bfloat16(a1));
    aggout[(size_t)node * 64 + lane] = lo | (hi << 16);
}

// ---------------- layer 1: h = relu([agg|x] @ [Wrel|Wroot]^T + b1), bf16 out ----------------
// block = 256 (4 waves), M-tile 64 (16 rows/wave), N-tile 128, K=256 in 2 phases
__global__ __launch_bounds__(256) void gemm1_kernel(
    const unsigned short* __restrict__ aggb,  // [N][128] bf16 bits
    const unsigned short* __restrict__ xb,    // [N][128]
    const unsigned short* __restrict__ Wrel,  // [128][128]
    const unsigned short* __restrict__ Wroot, // [128][128]
    const float* __restrict__ b1,             // [128]
    unsigned short* __restrict__ hb,          // [N][128] bf16 out
    int nN)
{
    __shared__ __align__(16) unsigned char lds[32768];
    int tid = threadIdx.x;
    int wave = tid >> 6, lane = tid & 63;
    int i0 = blockIdx.x * 64 + wave * 16;
    int mrow = lane & 15, kslot = lane >> 4;
    int arow = i0 + mrow; if (arow >= nN) arow = 0;

    f32x4 acc[8] = {};
    const unsigned short* Asrc[2] = {aggb, xb};
    const unsigned short* Wsrc[2] = {Wrel, Wroot};

    for (int ph = 0; ph < 2; ++ph) {
        __syncthreads();
        const uint4* src = (const uint4*)Wsrc[ph];
        for (int c = tid; c < 2048; c += 256) {
            int row = c >> 4;
            int off = (c & 15) << 4;
            *(uint4*)(&lds[row * 256 + (off ^ ((row & 7) << 4))]) = src[c];
        }
        __syncthreads();
        const unsigned short* Ap = Asrc[ph] + (size_t)arow * 128 + kslot * 8;
        #pragma unroll
        for (int t = 0; t < 4; ++t) {
            bf16x8 a = *(const bf16x8*)(Ap + t * 32);
            #pragma unroll
            for (int ct = 0; ct < 8; ++ct) {
                int o = ct * 16 + mrow;
                int off = (t * 64 + kslot * 16) ^ ((o & 7) << 4);
                bf16x8 b = *(const bf16x8*)(&lds[o * 256 + off]);
                acc[ct] = __builtin_amdgcn_mfma_f32_16x16x32_bf16(a, b, acc[ct], 0, 0, 0);
            }
        }
    }
    // epilogue: bias + relu, store bf16
    #pragma unroll
    for (int ct = 0; ct < 8; ++ct) {
        int col = ct * 16 + mrow;
        float bias = b1[col];
        #pragma unroll
        for (int r = 0; r < 4; ++r) {
            int row = i0 + kslot * 4 + r;
            if (row < nN) {
                float v = fmaxf(acc[ct][r] + bias, 0.f);
                hb[(size_t)row * 128 + col] =
                    __builtin_bit_cast(unsigned short, __float2bfloat16(v));
            }
        }
    }
}

// ---------------- layer 2: log_softmax([agg2|h] @ W2cat^T + b2) ----------------
// C padded to 48 (3 col-tiles); fused in-register log-softmax
__global__ __launch_bounds__(256) void gemm2_lsm_kernel(
    const unsigned short* __restrict__ aggb,  // [N][128]
    const unsigned short* __restrict__ hb,    // [N][128]
    const unsigned short* __restrict__ W2cat, // [48][256]
    const float* __restrict__ b2,             // [40]
    float* __restrict__ out,                  // [N][40]
    int nN)
{
    __shared__ __align__(16) unsigned char lds[24576];
    int tid = threadIdx.x;
    int wave = tid >> 6, lane = tid & 63;
    int i0 = blockIdx.x * 64 + wave * 16;
    int mrow = lane & 15, kslot = lane >> 4;
    int arow = i0 + mrow; if (arow >= nN) arow = 0;

    for (int c = tid; c < 1536; c += 256) {
        int row = c >> 5;
        int off = (c & 31) << 4;
        *(uint4*)(&lds[row * 512 + (off ^ ((row & 7) << 4))]) = ((const uint4*)W2cat)[c];
    }
    __syncthreads();

    f32x4 acc[3] = {};
    #pragma unroll
    for (int t = 0; t < 8; ++t) {
        const unsigned short* A = (t < 4) ? aggb : hb;
        int kk = (t & 3) * 32 + kslot * 8;
        bf16x8 a = *(const bf16x8*)(A + (size_t)arow * 128 + kk);
        #pragma unroll
        for (int ct = 0; ct < 3; ++ct) {
            int o = ct * 16 + mrow;
            int off = (t * 64 + kslot * 16) ^ ((o & 7) << 4);
            bf16x8 b = *(const bf16x8*)(&lds[o * 512 + off]);
            acc[ct] = __builtin_amdgcn_mfma_f32_16x16x32_bf16(a, b, acc[ct], 0, 0, 0);
        }
    }

    float lg[3][4];
    #pragma unroll
    for (int ct = 0; ct < 3; ++ct) {
        int col = ct * 16 + mrow;
        float bias = (col < 40) ? b2[col] : 0.f;
        #pragma unroll
        for (int r = 0; r < 4; ++r)
            lg[ct][r] = (col < 40) ? (acc[ct][r] + bias) : -INFINITY;
    }
    #pragma unroll
    for (int r = 0; r < 4; ++r) {
        float m = fmaxf(fmaxf(lg[0][r], lg[1][r]), lg[2][r]);
        #pragma unroll
        for (int off = 8; off >= 1; off >>= 1) m = fmaxf(m, __shfl_xor(m, off));
        float s = expf(lg[0][r] - m) + expf(lg[1][r] - m) + expf(lg[2][r] - m);
        #pragma unroll
        for (int off = 8; off >= 1; off >>= 1) s += __shfl_xor(s, off);
        float lse = m + logf(s);
        int row = i0 + kslot * 4 + r;
        if (row < nN) {
            #pragma unroll
            for (int ct = 0; ct < 3; ++ct) {
                int col = ct * 16 + mrow;
                if (col < 40) out[(size_t)row * 40 + col] = lg[ct][r] - lse;
            }
        }
    }
}

// ---------------- launch ----------------

extern "C" void kernel_launch(void* const* d_in, const int* in_sizes, int n_in,
                              void* d_out, int out_size, void* d_ws, size_t ws_size,
                              hipStream_t stream)
{
    const float* x       = (const float*)d_in[0];
    const int*   ei      = (const int*)d_in[1];
    const float* W1_rel  = (const float*)d_in[2];
    const float* b1      = (const float*)d_in[3];
    const float* W1_root = (const float*)d_in[4];
    const float* W2_rel  = (const float*)d_in[5];
    const float* b2      = (const float*)d_in[6];
    const float* W2_root = (const float*)d_in[7];

    int N = in_sizes[0] / 128;
    int E = in_sizes[1] / 2;
    const int* srcp = ei;
    const int* dstp = ei + E;

    size_t nf = (size_t)N * 128;
    unsigned short* xb      = (unsigned short*)d_ws;   // [N][128] bf16
    unsigned short* aggb    = xb + nf;                 // [N][128]
    unsigned short* hb      = aggb + nf;               // [N][128]
    unsigned short* W1relB  = hb + nf;                 // 16384
    unsigned short* W1rootB = W1relB + 16384;          // 16384
    unsigned short* W2cat   = W1rootB + 16384;         // 12288
    int* rowptr     = (int*)(W2cat + 12288);           // [N+1]
    int* cursor     = rowptr + (N + 1);                // [N]
    int* sorted_src = cursor + N;                      // [E]

    size_t needed = 3 * nf * sizeof(unsigned short)
                  + (16384 + 16384 + 12288) * sizeof(unsigned short)
                  + (size_t)(2 * N + 1 + E) * sizeof(int);
    if (ws_size < needed) return;

    // CSR build (by destination)
    hipMemsetAsync(cursor, 0, (size_t)N * sizeof(int), stream);
    hist_kernel<<<(E + 255) / 256, 256, 0, stream>>>(dstp, cursor, E, N);
    scan_kernel<<<1, 1024, 0, stream>>>(cursor, rowptr, cursor, N);
    fill_kernel<<<(E + 255) / 256, 256, 0, stream>>>(srcp, dstp, cursor, sorted_src, E, N);

    // conversions
    cvt_bf16_kernel<<<2048, 256, 0, stream>>>((const float4*)x, (ushort4*)xb, (int)(nf / 4));
    prep_weights_kernel<<<(45056 + 255) / 256, 256, 0, stream>>>(
        W1_rel, W1_root, W2_rel, W2_root, W1relB, W1rootB, W2cat);

    // layer 1
    aggregate_bf16_kernel<<<(N + 3) / 4, 256, 0, stream>>>(
        (const uint32*)xb, rowptr, sorted_src, (uint32*)aggb, N);
    gemm1_kernel<<<(N + 63) / 64, 256, 0, stream>>>(
        aggb, xb, W1relB, W1rootB, b1, hb, N);

    // layer 2
    aggregate_bf16_kernel<<<(N + 3) / 4, 256, 0, stream>>>(
        (const uint32*)hb, rowptr, sorted_src, (uint32*)aggb, N);
    gemm2_lsm_kernel<<<(N + 63) / 64, 256, 0, stream>>>(
        aggb, hb, W2cat, b2, (float*)d_out, N);
}

// Round 4
// 405.092 us; speedup vs baseline: 15.9292x; 1.5379x over previous
//
#include <hip/hip_runtime.h>
#include <hip/hip_bf16.h>
#include <math.h>

// N = 100000, E = 1600000, F_IN = H = 128, C = 40
typedef __bf16 bf16x8 __attribute__((ext_vector_type(8)));
typedef float f32x4 __attribute__((ext_vector_type(4)));
typedef unsigned int uint32;

// ---------------- CSR build ----------------

__global__ __launch_bounds__(256) void hist_kernel(
    const int* __restrict__ dst, int* __restrict__ cnt, int nE, int nN)
{
    int e = blockIdx.x * blockDim.x + threadIdx.x;
    if (e >= nE) return;
    int d = dst[e];
    if ((unsigned)d < (unsigned)nN) atomicAdd(&cnt[d], 1);
}

// phase 1: per-block (1024 elements) sums
__global__ __launch_bounds__(256) void csr_partial_kernel(
    const int* __restrict__ cnt, int* __restrict__ blocksum, int nN)
{
    int b = blockIdx.x, t = threadIdx.x;
    int base = b * 1024 + t * 4;
    int s = 0;
    #pragma unroll
    for (int k = 0; k < 4; ++k) { int i = base + k; if (i < nN) s += cnt[i]; }
    #pragma unroll
    for (int off = 1; off < 64; off <<= 1) s += __shfl_xor(s, off);
    __shared__ int ws[4];
    int lane = t & 63, w = t >> 6;
    if (lane == 0) ws[w] = s;
    __syncthreads();
    if (t == 0) blocksum[b] = ws[0] + ws[1] + ws[2] + ws[3];
}

// phase 2: scan the (<=1024) block sums; also writes rowptr[nN] = total
__global__ __launch_bounds__(1024) void csr_scanblocks_kernel(
    const int* __restrict__ blocksum, int* __restrict__ blockpre,
    int nB, int* __restrict__ rowptr, int nN)
{
    __shared__ int sm[1024];
    int t = threadIdx.x;
    int v = (t < nB) ? blocksum[t] : 0;
    sm[t] = v;
    __syncthreads();
    for (int off = 1; off < 1024; off <<= 1) {
        int u = (t >= off) ? sm[t - off] : 0;
        __syncthreads();
        sm[t] += u;
        __syncthreads();
    }
    if (t < nB) blockpre[t] = sm[t] - v;     // exclusive prefix
    if (t == 1023) rowptr[nN] = sm[1023];    // grand total
}

// phase 3: per-block exclusive scan + global offset -> rowptr, cursor
__global__ __launch_bounds__(256) void csr_scanfinal_kernel(
    const int* __restrict__ cnt, const int* __restrict__ blockpre,
    int* __restrict__ rowptr, int* __restrict__ cursor, int nN)
{
    int b = blockIdx.x, t = threadIdx.x;
    int base = b * 1024 + t * 4;
    int c[4]; int s = 0;
    #pragma unroll
    for (int k = 0; k < 4; ++k) { int i = base + k; c[k] = (i < nN) ? cnt[i] : 0; s += c[k]; }
    int lane = t & 63, w = t >> 6;
    int inc = s;
    #pragma unroll
    for (int off = 1; off < 64; off <<= 1) {
        int u = __shfl_up(inc, off);
        if (lane >= off) inc += u;
    }
    __shared__ int ws[4];
    if (lane == 63) ws[w] = inc;
    __syncthreads();
    int wpre = 0;
    for (int i = 0; i < w; ++i) wpre += ws[i];
    int run = blockpre[b] + wpre + (inc - s);
    #pragma unroll
    for (int k = 0; k < 4; ++k) {
        int i = base + k;
        if (i < nN) { rowptr[i] = run; cursor[i] = run; run += c[k]; }
    }
}

__global__ __launch_bounds__(256) void fill_kernel(
    const int* __restrict__ src, const int* __restrict__ dst,
    int* __restrict__ cursor, int* __restrict__ sorted_src, int nE, int nN)
{
    int e = blockIdx.x * blockDim.x + threadIdx.x;
    if (e >= nE) return;
    int d = dst[e];
    if ((unsigned)d >= (unsigned)nN) return;
    int pos = atomicAdd(&cursor[d], 1);
    sorted_src[pos] = src[e];
}

// ---------------- conversions ----------------

__global__ __launch_bounds__(256) void cvt_bf16_kernel(
    const float4* __restrict__ in, ushort4* __restrict__ out, int n4)
{
    int i = blockIdx.x * blockDim.x + threadIdx.x;
    int stride = gridDim.x * blockDim.x;
    for (; i < n4; i += stride) {
        float4 v = in[i];
        ushort4 o;
        o.x = __builtin_bit_cast(unsigned short, __float2bfloat16(v.x));
        o.y = __builtin_bit_cast(unsigned short, __float2bfloat16(v.y));
        o.z = __builtin_bit_cast(unsigned short, __float2bfloat16(v.z));
        o.w = __builtin_bit_cast(unsigned short, __float2bfloat16(v.w));
        out[i] = o;
    }
}

// W1relB[128*128], W1rootB[128*128], W2cat[48*256] (rows>=40 zero)
__global__ __launch_bounds__(256) void prep_weights_kernel(
    const float* __restrict__ W1_rel, const float* __restrict__ W1_root,
    const float* __restrict__ W2_rel, const float* __restrict__ W2_root,
    unsigned short* __restrict__ W1relB, unsigned short* __restrict__ W1rootB,
    unsigned short* __restrict__ W2cat)
{
    int i = blockIdx.x * 256 + threadIdx.x;
    if (i < 16384) {
        W1relB[i] = __builtin_bit_cast(unsigned short, __float2bfloat16(W1_rel[i]));
    } else if (i < 32768) {
        int j = i - 16384;
        W1rootB[j] = __builtin_bit_cast(unsigned short, __float2bfloat16(W1_root[j]));
    } else if (i < 32768 + 12288) {
        int j = i - 32768;
        int o = j >> 8, k = j & 255;
        float v = 0.f;
        if (o < 40) v = (k < 128) ? W2_rel[o * 128 + k] : W2_root[o * 128 + (k - 128)];
        W2cat[j] = __builtin_bit_cast(unsigned short, __float2bfloat16(v));
    }
}

// ---------------- gather aggregation (bf16 in, bf16 out, f32 accum) ----------------

__global__ __launch_bounds__(256) void aggregate_bf16_kernel(
    const uint32* __restrict__ xin,       // [N][64] (2 bf16 / uint)
    const int* __restrict__ rowptr,
    const int* __restrict__ sorted_src,
    uint32* __restrict__ aggout,          // [N][64]
    int nN)
{
    int wave = threadIdx.x >> 6;
    int lane = threadIdx.x & 63;
    int node = blockIdx.x * 4 + wave;
    if (node >= nN) return;
    int beg = rowptr[node], end = rowptr[node + 1];
    float a0 = 0.f, a1 = 0.f, b0 = 0.f, b1 = 0.f;
    int j = beg;
    for (; j + 4 <= end; j += 4) {
        int s0 = sorted_src[j], s1 = sorted_src[j + 1];
        int s2 = sorted_src[j + 2], s3 = sorted_src[j + 3];
        uint32 u0 = xin[(size_t)s0 * 64 + lane];
        uint32 u1 = xin[(size_t)s1 * 64 + lane];
        uint32 u2 = xin[(size_t)s2 * 64 + lane];
        uint32 u3 = xin[(size_t)s3 * 64 + lane];
        a0 += __uint_as_float(u0 << 16);
        a1 += __uint_as_float(u0 & 0xffff0000u);
        b0 += __uint_as_float(u1 << 16);
        b1 += __uint_as_float(u1 & 0xffff0000u);
        a0 += __uint_as_float(u2 << 16);
        a1 += __uint_as_float(u2 & 0xffff0000u);
        b0 += __uint_as_float(u3 << 16);
        b1 += __uint_as_float(u3 & 0xffff0000u);
    }
    for (; j < end; ++j) {
        uint32 u = xin[(size_t)sorted_src[j] * 64 + lane];
        a0 += __uint_as_float(u << 16);
        a1 += __uint_as_float(u & 0xffff0000u);
    }
    a0 += b0; a1 += b1;
    uint32 lo = __builtin_bit_cast(unsigned short, __float2bfloat16(a0));
    uint32 hi = __builtin_bit_cast(unsigned short, __float2bfloat16(a1));
    aggout[(size_t)node * 64 + lane] = lo | (hi << 16);
}

// ---------------- layer 1 GEMM ----------------

__global__ __launch_bounds__(256) void gemm1_kernel(
    const unsigned short* __restrict__ aggb,
    const unsigned short* __restrict__ xb,
    const unsigned short* __restrict__ Wrel,
    const unsigned short* __restrict__ Wroot,
    const float* __restrict__ b1,
    unsigned short* __restrict__ hb,
    int nN)
{
    __shared__ __align__(16) unsigned char lds[32768];
    int tid = threadIdx.x;
    int wave = tid >> 6, lane = tid & 63;
    int i0 = blockIdx.x * 64 + wave * 16;
    int mrow = lane & 15, kslot = lane >> 4;
    int arow = i0 + mrow; if (arow >= nN) arow = 0;

    f32x4 acc[8] = {};
    const unsigned short* Asrc[2] = {aggb, xb};
    const unsigned short* Wsrc[2] = {Wrel, Wroot};

    for (int ph = 0; ph < 2; ++ph) {
        __syncthreads();
        const uint4* src = (const uint4*)Wsrc[ph];
        for (int c = tid; c < 2048; c += 256) {
            int row = c >> 4;
            int off = (c & 15) << 4;
            *(uint4*)(&lds[row * 256 + (off ^ ((row & 7) << 4))]) = src[c];
        }
        __syncthreads();
        const unsigned short* Ap = Asrc[ph] + (size_t)arow * 128 + kslot * 8;
        #pragma unroll
        for (int t = 0; t < 4; ++t) {
            bf16x8 a = *(const bf16x8*)(Ap + t * 32);
            #pragma unroll
            for (int ct = 0; ct < 8; ++ct) {
                int o = ct * 16 + mrow;
                int off = (t * 64 + kslot * 16) ^ ((o & 7) << 4);
                bf16x8 b = *(const bf16x8*)(&lds[o * 256 + off]);
                acc[ct] = __builtin_amdgcn_mfma_f32_16x16x32_bf16(a, b, acc[ct], 0, 0, 0);
            }
        }
    }
    #pragma unroll
    for (int ct = 0; ct < 8; ++ct) {
        int col = ct * 16 + mrow;
        float bias = b1[col];
        #pragma unroll
        for (int r = 0; r < 4; ++r) {
            int row = i0 + kslot * 4 + r;
            if (row < nN) {
                float v = fmaxf(acc[ct][r] + bias, 0.f);
                hb[(size_t)row * 128 + col] =
                    __builtin_bit_cast(unsigned short, __float2bfloat16(v));
            }
        }
    }
}

// ---------------- layer 2 GEMM + log_softmax ----------------

__global__ __launch_bounds__(256) void gemm2_lsm_kernel(
    const unsigned short* __restrict__ aggb,
    const unsigned short* __restrict__ hb,
    const unsigned short* __restrict__ W2cat,  // [48][256]
    const float* __restrict__ b2,
    float* __restrict__ out,
    int nN)
{
    __shared__ __align__(16) unsigned char lds[24576];
    int tid = threadIdx.x;
    int wave = tid >> 6, lane = tid & 63;
    int i0 = blockIdx.x * 64 + wave * 16;
    int mrow = lane & 15, kslot = lane >> 4;
    int arow = i0 + mrow; if (arow >= nN) arow = 0;

    for (int c = tid; c < 1536; c += 256) {
        int row = c >> 5;
        int off = (c & 31) << 4;
        *(uint4*)(&lds[row * 512 + (off ^ ((row & 7) << 4))]) = ((const uint4*)W2cat)[c];
    }
    __syncthreads();

    f32x4 acc[3] = {};
    #pragma unroll
    for (int t = 0; t < 8; ++t) {
        const unsigned short* A = (t < 4) ? aggb : hb;
        int kk = (t & 3) * 32 + kslot * 8;
        bf16x8 a = *(const bf16x8*)(A + (size_t)arow * 128 + kk);
        #pragma unroll
        for (int ct = 0; ct < 3; ++ct) {
            int o = ct * 16 + mrow;
            int off = (t * 64 + kslot * 16) ^ ((o & 7) << 4);
            bf16x8 b = *(const bf16x8*)(&lds[o * 512 + off]);
            acc[ct] = __builtin_amdgcn_mfma_f32_16x16x32_bf16(a, b, acc[ct], 0, 0, 0);
        }
    }

    float lg[3][4];
    #pragma unroll
    for (int ct = 0; ct < 3; ++ct) {
        int col = ct * 16 + mrow;
        float bias = (col < 40) ? b2[col] : 0.f;
        #pragma unroll
        for (int r = 0; r < 4; ++r)
            lg[ct][r] = (col < 40) ? (acc[ct][r] + bias) : -INFINITY;
    }
    #pragma unroll
    for (int r = 0; r < 4; ++r) {
        float m = fmaxf(fmaxf(lg[0][r], lg[1][r]), lg[2][r]);
        #pragma unroll
        for (int off = 8; off >= 1; off >>= 1) m = fmaxf(m, __shfl_xor(m, off));
        float s = expf(lg[0][r] - m) + expf(lg[1][r] - m) + expf(lg[2][r] - m);
        #pragma unroll
        for (int off = 8; off >= 1; off >>= 1) s += __shfl_xor(s, off);
        float lse = m + logf(s);
        int row = i0 + kslot * 4 + r;
        if (row < nN) {
            #pragma unroll
            for (int ct = 0; ct < 3; ++ct) {
                int col = ct * 16 + mrow;
                if (col < 40) out[(size_t)row * 40 + col] = lg[ct][r] - lse;
            }
        }
    }
}

// ---------------- launch ----------------

extern "C" void kernel_launch(void* const* d_in, const int* in_sizes, int n_in,
                              void* d_out, int out_size, void* d_ws, size_t ws_size,
                              hipStream_t stream)
{
    const float* x       = (const float*)d_in[0];
    const int*   ei      = (const int*)d_in[1];
    const float* W1_rel  = (const float*)d_in[2];
    const float* b1      = (const float*)d_in[3];
    const float* W1_root = (const float*)d_in[4];
    const float* W2_rel  = (const float*)d_in[5];
    const float* b2      = (const float*)d_in[6];
    const float* W2_root = (const float*)d_in[7];

    int N = in_sizes[0] / 128;
    int E = in_sizes[1] / 2;
    const int* srcp = ei;
    const int* dstp = ei + E;

    int nB = (N + 1023) / 1024;   // scan blocks

    size_t nf = (size_t)N * 128;
    unsigned short* xb      = (unsigned short*)d_ws;   // [N][128] bf16
    unsigned short* aggb    = xb + nf;                 // [N][128]
    unsigned short* hb      = aggb + nf;               // [N][128]
    unsigned short* W1relB  = hb + nf;                 // 16384
    unsigned short* W1rootB = W1relB + 16384;          // 16384
    unsigned short* W2cat   = W1rootB + 16384;         // 12288
    int* rowptr     = (int*)(W2cat + 12288);           // [N+1]
    int* cursor     = rowptr + (N + 1);                // [N]
    int* blocksum   = cursor + N;                      // [nB]
    int* blockpre   = blocksum + nB;                   // [nB]
    int* sorted_src = blockpre + nB;                   // [E]

    size_t needed = 3 * nf * sizeof(unsigned short)
                  + (16384 + 16384 + 12288) * sizeof(unsigned short)
                  + (size_t)(2 * N + 1 + 2 * nB + E) * sizeof(int);
    if (ws_size < needed) return;

    // CSR build (by destination)
    hipMemsetAsync(cursor, 0, (size_t)N * sizeof(int), stream);
    hist_kernel<<<(E + 255) / 256, 256, 0, stream>>>(dstp, cursor, E, N);
    csr_partial_kernel<<<nB, 256, 0, stream>>>(cursor, blocksum, N);
    csr_scanblocks_kernel<<<1, 1024, 0, stream>>>(blocksum, blockpre, nB, rowptr, N);
    csr_scanfinal_kernel<<<nB, 256, 0, stream>>>(cursor, blockpre, rowptr, cursor, N);
    fill_kernel<<<(E + 255) / 256, 256, 0, stream>>>(srcp, dstp, cursor, sorted_src, E, N);

    // conversions
    cvt_bf16_kernel<<<2048, 256, 0, stream>>>((const float4*)x, (ushort4*)xb, (int)(nf / 4));
    prep_weights_kernel<<<(45056 + 255) / 256, 256, 0, stream>>>(
        W1_rel, W1_root, W2_rel, W2_root, W1relB, W1rootB, W2cat);

    // layer 1
    aggregate_bf16_kernel<<<(N + 3) / 4, 256, 0, stream>>>(
        (const uint32*)xb, rowptr, sorted_src, (uint32*)aggb, N);
    gemm1_kernel<<<(N + 63) / 64, 256, 0, stream>>>(
        aggb, xb, W1relB, W1rootB, b1, hb, N);

    // layer 2
    aggregate_bf16_kernel<<<(N + 3) / 4, 256, 0, stream>>>(
        (const uint32*)hb, rowptr, sorted_src, (uint32*)aggb, N);
    gemm2_lsm_kernel<<<(N + 63) / 64, 256, 0, stream>>>(
        aggb, hb, W2cat, b2, (float*)d_out, N);
}

// Round 5
// 346.772 us; speedup vs baseline: 18.6081x; 1.1682x over previous
//
#include <hip/hip_runtime.h>
#include <hip/hip_bf16.h>
#include <math.h>

// N = 100000, E = 1600000, F_IN = H = 128, C = 40
typedef __bf16 bf16x8 __attribute__((ext_vector_type(8)));
typedef float f32x4 __attribute__((ext_vector_type(4)));
typedef unsigned int uint32;

#define FILL_RANGES 16
#define FILL_CHUNK  4096

// ---------------- CSR build ----------------

// counts per node AND records each edge's rank within its destination
__global__ __launch_bounds__(256) void hist_rank_kernel(
    const int* __restrict__ dst, int* __restrict__ cnt,
    int* __restrict__ rank, int nE, int nN)
{
    int e = blockIdx.x * blockDim.x + threadIdx.x;
    if (e >= nE) return;
    int d = dst[e];
    if ((unsigned)d < (unsigned)nN) rank[e] = atomicAdd(&cnt[d], 1);
}

// phase 1: per-block (1024 elements) sums
__global__ __launch_bounds__(256) void csr_partial_kernel(
    const int* __restrict__ cnt, int* __restrict__ blocksum, int nN)
{
    int b = blockIdx.x, t = threadIdx.x;
    int base = b * 1024 + t * 4;
    int s = 0;
    #pragma unroll
    for (int k = 0; k < 4; ++k) { int i = base + k; if (i < nN) s += cnt[i]; }
    #pragma unroll
    for (int off = 1; off < 64; off <<= 1) s += __shfl_xor(s, off);
    __shared__ int ws[4];
    int lane = t & 63, w = t >> 6;
    if (lane == 0) ws[w] = s;
    __syncthreads();
    if (t == 0) blocksum[b] = ws[0] + ws[1] + ws[2] + ws[3];
}

// phase 2: scan the (<=1024) block sums; also writes rowptr[nN] = total
__global__ __launch_bounds__(1024) void csr_scanblocks_kernel(
    const int* __restrict__ blocksum, int* __restrict__ blockpre,
    int nB, int* __restrict__ rowptr, int nN)
{
    __shared__ int sm[1024];
    int t = threadIdx.x;
    int v = (t < nB) ? blocksum[t] : 0;
    sm[t] = v;
    __syncthreads();
    for (int off = 1; off < 1024; off <<= 1) {
        int u = (t >= off) ? sm[t - off] : 0;
        __syncthreads();
        sm[t] += u;
        __syncthreads();
    }
    if (t < nB) blockpre[t] = sm[t] - v;     // exclusive prefix
    if (t == 1023) rowptr[nN] = sm[1023];    // grand total
}

// phase 3: per-block exclusive scan + global offset -> rowptr
__global__ __launch_bounds__(256) void csr_scanfinal_kernel(
    const int* __restrict__ cnt, const int* __restrict__ blockpre,
    int* __restrict__ rowptr, int nN)
{
    int b = blockIdx.x, t = threadIdx.x;
    int base = b * 1024 + t * 4;
    int c[4]; int s = 0;
    #pragma unroll
    for (int k = 0; k < 4; ++k) { int i = base + k; c[k] = (i < nN) ? cnt[i] : 0; s += c[k]; }
    int lane = t & 63, w = t >> 6;
    int inc = s;
    #pragma unroll
    for (int off = 1; off < 64; off <<= 1) {
        int u = __shfl_up(inc, off);
        if (lane >= off) inc += u;
    }
    __shared__ int ws[4];
    if (lane == 63) ws[w] = inc;
    __syncthreads();
    int wpre = 0;
    for (int i = 0; i < w; ++i) wpre += ws[i];
    int run = blockpre[b] + wpre + (inc - s);
    #pragma unroll
    for (int k = 0; k < 4; ++k) {
        int i = base + k;
        if (i < nN) { rowptr[i] = run; run += c[k]; }
    }
}

// range-partitioned, atomic-free fill: pass p only writes dst in its slice,
// confining scatter writes to a ~400KB window that lives in L2.
__global__ __launch_bounds__(256) void fill_ranged_kernel(
    const int* __restrict__ src, const int* __restrict__ dst,
    const int* __restrict__ rowptr, const int* __restrict__ rank,
    int* __restrict__ sorted_src, int nE, int nN, int nChunks, int rangeSz)
{
    int range = blockIdx.x / nChunks;
    int chunk = blockIdx.x - range * nChunks;
    int lo = range * rangeSz;
    int hi = lo + rangeSz;
    int e1 = chunk * FILL_CHUNK + FILL_CHUNK; if (e1 > nE) e1 = nE;
    for (int e = chunk * FILL_CHUNK + threadIdx.x; e < e1; e += 256) {
        int d = dst[e];
        if (d >= lo && d < hi && (unsigned)d < (unsigned)nN)
            sorted_src[rowptr[d] + rank[e]] = src[e];
    }
}

// ---------------- conversions ----------------

__global__ __launch_bounds__(256) void cvt_bf16_kernel(
    const float4* __restrict__ in, ushort4* __restrict__ out, int n4)
{
    int i = blockIdx.x * blockDim.x + threadIdx.x;
    int stride = gridDim.x * blockDim.x;
    for (; i < n4; i += stride) {
        float4 v = in[i];
        ushort4 o;
        o.x = __builtin_bit_cast(unsigned short, __float2bfloat16(v.x));
        o.y = __builtin_bit_cast(unsigned short, __float2bfloat16(v.y));
        o.z = __builtin_bit_cast(unsigned short, __float2bfloat16(v.z));
        o.w = __builtin_bit_cast(unsigned short, __float2bfloat16(v.w));
        out[i] = o;
    }
}

// W1relB[128*128], W1rootB[128*128], W2cat[48*256] (rows>=40 zero)
__global__ __launch_bounds__(256) void prep_weights_kernel(
    const float* __restrict__ W1_rel, const float* __restrict__ W1_root,
    const float* __restrict__ W2_rel, const float* __restrict__ W2_root,
    unsigned short* __restrict__ W1relB, unsigned short* __restrict__ W1rootB,
    unsigned short* __restrict__ W2cat)
{
    int i = blockIdx.x * 256 + threadIdx.x;
    if (i < 16384) {
        W1relB[i] = __builtin_bit_cast(unsigned short, __float2bfloat16(W1_rel[i]));
    } else if (i < 32768) {
        int j = i - 16384;
        W1rootB[j] = __builtin_bit_cast(unsigned short, __float2bfloat16(W1_root[j]));
    } else if (i < 32768 + 12288) {
        int j = i - 32768;
        int o = j >> 8, k = j & 255;
        float v = 0.f;
        if (o < 40) v = (k < 128) ? W2_rel[o * 128 + k] : W2_root[o * 128 + (k - 128)];
        W2cat[j] = __builtin_bit_cast(unsigned short, __float2bfloat16(v));
    }
}

// ---------------- gather aggregation (bf16 in, bf16 out, f32 accum) ----------------

__global__ __launch_bounds__(256) void aggregate_bf16_kernel(
    const uint32* __restrict__ xin,       // [N][64] (2 bf16 / uint)
    const int* __restrict__ rowptr,
    const int* __restrict__ sorted_src,
    uint32* __restrict__ aggout,          // [N][64]
    int nN)
{
    int wave = threadIdx.x >> 6;
    int lane = threadIdx.x & 63;
    int node = blockIdx.x * 4 + wave;
    if (node >= nN) return;
    int beg = rowptr[node], end = rowptr[node + 1];
    float a0 = 0.f, a1 = 0.f, b0 = 0.f, b1 = 0.f;
    int j = beg;
    for (; j + 4 <= end; j += 4) {
        int s0 = sorted_src[j], s1 = sorted_src[j + 1];
        int s2 = sorted_src[j + 2], s3 = sorted_src[j + 3];
        uint32 u0 = xin[(size_t)s0 * 64 + lane];
        uint32 u1 = xin[(size_t)s1 * 64 + lane];
        uint32 u2 = xin[(size_t)s2 * 64 + lane];
        uint32 u3 = xin[(size_t)s3 * 64 + lane];
        a0 += __uint_as_float(u0 << 16);
        a1 += __uint_as_float(u0 & 0xffff0000u);
        b0 += __uint_as_float(u1 << 16);
        b1 += __uint_as_float(u1 & 0xffff0000u);
        a0 += __uint_as_float(u2 << 16);
        a1 += __uint_as_float(u2 & 0xffff0000u);
        b0 += __uint_as_float(u3 << 16);
        b1 += __uint_as_float(u3 & 0xffff0000u);
    }
    for (; j < end; ++j) {
        uint32 u = xin[(size_t)sorted_src[j] * 64 + lane];
        a0 += __uint_as_float(u << 16);
        a1 += __uint_as_float(u & 0xffff0000u);
    }
    a0 += b0; a1 += b1;
    uint32 lo = __builtin_bit_cast(unsigned short, __float2bfloat16(a0));
    uint32 hi = __builtin_bit_cast(unsigned short, __float2bfloat16(a1));
    aggout[(size_t)node * 64 + lane] = lo | (hi << 16);
}

// ---------------- layer 1 GEMM ----------------

__global__ __launch_bounds__(256) void gemm1_kernel(
    const unsigned short* __restrict__ aggb,
    const unsigned short* __restrict__ xb,
    const unsigned short* __restrict__ Wrel,
    const unsigned short* __restrict__ Wroot,
    const float* __restrict__ b1,
    unsigned short* __restrict__ hb,
    int nN)
{
    __shared__ __align__(16) unsigned char lds[32768];
    int tid = threadIdx.x;
    int wave = tid >> 6, lane = tid & 63;
    int i0 = blockIdx.x * 64 + wave * 16;
    int mrow = lane & 15, kslot = lane >> 4;
    int arow = i0 + mrow; if (arow >= nN) arow = 0;

    f32x4 acc[8] = {};
    const unsigned short* Asrc[2] = {aggb, xb};
    const unsigned short* Wsrc[2] = {Wrel, Wroot};

    for (int ph = 0; ph < 2; ++ph) {
        __syncthreads();
        const uint4* src = (const uint4*)Wsrc[ph];
        for (int c = tid; c < 2048; c += 256) {
            int row = c >> 4;
            int off = (c & 15) << 4;
            *(uint4*)(&lds[row * 256 + (off ^ ((row & 7) << 4))]) = src[c];
        }
        __syncthreads();
        const unsigned short* Ap = Asrc[ph] + (size_t)arow * 128 + kslot * 8;
        #pragma unroll
        for (int t = 0; t < 4; ++t) {
            bf16x8 a = *(const bf16x8*)(Ap + t * 32);
            #pragma unroll
            for (int ct = 0; ct < 8; ++ct) {
                int o = ct * 16 + mrow;
                int off = (t * 64 + kslot * 16) ^ ((o & 7) << 4);
                bf16x8 b = *(const bf16x8*)(&lds[o * 256 + off]);
                acc[ct] = __builtin_amdgcn_mfma_f32_16x16x32_bf16(a, b, acc[ct], 0, 0, 0);
            }
        }
    }
    #pragma unroll
    for (int ct = 0; ct < 8; ++ct) {
        int col = ct * 16 + mrow;
        float bias = b1[col];
        #pragma unroll
        for (int r = 0; r < 4; ++r) {
            int row = i0 + kslot * 4 + r;
            if (row < nN) {
                float v = fmaxf(acc[ct][r] + bias, 0.f);
                hb[(size_t)row * 128 + col] =
                    __builtin_bit_cast(unsigned short, __float2bfloat16(v));
            }
        }
    }
}

// ---------------- layer 2 GEMM + log_softmax ----------------

__global__ __launch_bounds__(256) void gemm2_lsm_kernel(
    const unsigned short* __restrict__ aggb,
    const unsigned short* __restrict__ hb,
    const unsigned short* __restrict__ W2cat,  // [48][256]
    const float* __restrict__ b2,
    float* __restrict__ out,
    int nN)
{
    __shared__ __align__(16) unsigned char lds[24576];
    int tid = threadIdx.x;
    int wave = tid >> 6, lane = tid & 63;
    int i0 = blockIdx.x * 64 + wave * 16;
    int mrow = lane & 15, kslot = lane >> 4;
    int arow = i0 + mrow; if (arow >= nN) arow = 0;

    for (int c = tid; c < 1536; c += 256) {
        int row = c >> 5;
        int off = (c & 31) << 4;
        *(uint4*)(&lds[row * 512 + (off ^ ((row & 7) << 4))]) = ((const uint4*)W2cat)[c];
    }
    __syncthreads();

    f32x4 acc[3] = {};
    #pragma unroll
    for (int t = 0; t < 8; ++t) {
        const unsigned short* A = (t < 4) ? aggb : hb;
        int kk = (t & 3) * 32 + kslot * 8;
        bf16x8 a = *(const bf16x8*)(A + (size_t)arow * 128 + kk);
        #pragma unroll
        for (int ct = 0; ct < 3; ++ct) {
            int o = ct * 16 + mrow;
            int off = (t * 64 + kslot * 16) ^ ((o & 7) << 4);
            bf16x8 b = *(const bf16x8*)(&lds[o * 512 + off]);
            acc[ct] = __builtin_amdgcn_mfma_f32_16x16x32_bf16(a, b, acc[ct], 0, 0, 0);
        }
    }

    float lg[3][4];
    #pragma unroll
    for (int ct = 0; ct < 3; ++ct) {
        int col = ct * 16 + mrow;
        float bias = (col < 40) ? b2[col] : 0.f;
        #pragma unroll
        for (int r = 0; r < 4; ++r)
            lg[ct][r] = (col < 40) ? (acc[ct][r] + bias) : -INFINITY;
    }
    #pragma unroll
    for (int r = 0; r < 4; ++r) {
        float m = fmaxf(fmaxf(lg[0][r], lg[1][r]), lg[2][r]);
        #pragma unroll
        for (int off = 8; off >= 1; off >>= 1) m = fmaxf(m, __shfl_xor(m, off));
        float s = expf(lg[0][r] - m) + expf(lg[1][r] - m) + expf(lg[2][r] - m);
        #pragma unroll
        for (int off = 8; off >= 1; off >>= 1) s += __shfl_xor(s, off);
        float lse = m + logf(s);
        int row = i0 + kslot * 4 + r;
        if (row < nN) {
            #pragma unroll
            for (int ct = 0; ct < 3; ++ct) {
                int col = ct * 16 + mrow;
                if (col < 40) out[(size_t)row * 40 + col] = lg[ct][r] - lse;
            }
        }
    }
}

// ---------------- launch ----------------

extern "C" void kernel_launch(void* const* d_in, const int* in_sizes, int n_in,
                              void* d_out, int out_size, void* d_ws, size_t ws_size,
                              hipStream_t stream)
{
    const float* x       = (const float*)d_in[0];
    const int*   ei      = (const int*)d_in[1];
    const float* W1_rel  = (const float*)d_in[2];
    const float* b1      = (const float*)d_in[3];
    const float* W1_root = (const float*)d_in[4];
    const float* W2_rel  = (const float*)d_in[5];
    const float* b2      = (const float*)d_in[6];
    const float* W2_root = (const float*)d_in[7];

    int N = in_sizes[0] / 128;
    int E = in_sizes[1] / 2;
    const int* srcp = ei;
    const int* dstp = ei + E;

    int nB = (N + 1023) / 1024;   // scan blocks

    size_t nf = (size_t)N * 128;
    unsigned short* xb      = (unsigned short*)d_ws;   // [N][128] bf16
    unsigned short* aggb    = xb + nf;                 // [N][128]
    unsigned short* hb      = aggb + nf;               // [N][128]
    unsigned short* W1relB  = hb + nf;                 // 16384
    unsigned short* W1rootB = W1relB + 16384;          // 16384
    unsigned short* W2cat   = W1rootB + 16384;         // 12288
    int* rowptr     = (int*)(W2cat + 12288);           // [N+1]
    int* cnt        = rowptr + (N + 1);                // [N]
    int* blocksum   = cnt + N;                         // [nB]
    int* blockpre   = blocksum + nB;                   // [nB]
    int* rank       = blockpre + nB;                   // [E]
    int* sorted_src = rank + E;                        // [E]

    size_t needed = 3 * nf * sizeof(unsigned short)
                  + (16384 + 16384 + 12288) * sizeof(unsigned short)
                  + (size_t)(2 * N + 1 + 2 * nB + 2 * (size_t)E) * sizeof(int);
    if (ws_size < needed) return;

    // CSR build (by destination)
    hipMemsetAsync(cnt, 0, (size_t)N * sizeof(int), stream);
    hist_rank_kernel<<<(E + 255) / 256, 256, 0, stream>>>(dstp, cnt, rank, E, N);
    csr_partial_kernel<<<nB, 256, 0, stream>>>(cnt, blocksum, N);
    csr_scanblocks_kernel<<<1, 1024, 0, stream>>>(blocksum, blockpre, nB, rowptr, N);
    csr_scanfinal_kernel<<<nB, 256, 0, stream>>>(cnt, blockpre, rowptr, N);
    {
        int nChunks = (E + FILL_CHUNK - 1) / FILL_CHUNK;
        int rangeSz = (N + FILL_RANGES - 1) / FILL_RANGES;
        fill_ranged_kernel<<<nChunks * FILL_RANGES, 256, 0, stream>>>(
            srcp, dstp, rowptr, rank, sorted_src, E, N, nChunks, rangeSz);
    }

    // conversions
    cvt_bf16_kernel<<<2048, 256, 0, stream>>>((const float4*)x, (ushort4*)xb, (int)(nf / 4));
    prep_weights_kernel<<<(45056 + 255) / 256, 256, 0, stream>>>(
        W1_rel, W1_root, W2_rel, W2_root, W1relB, W1rootB, W2cat);

    // layer 1
    aggregate_bf16_kernel<<<(N + 3) / 4, 256, 0, stream>>>(
        (const uint32*)xb, rowptr, sorted_src, (uint32*)aggb, N);
    gemm1_kernel<<<(N + 63) / 64, 256, 0, stream>>>(
        aggb, xb, W1relB, W1rootB, b1, hb, N);

    // layer 2
    aggregate_bf16_kernel<<<(N + 3) / 4, 256, 0, stream>>>(
        (const uint32*)hb, rowptr, sorted_src, (uint32*)aggb, N);
    gemm2_lsm_kernel<<<(N + 63) / 64, 256, 0, stream>>>(
        aggb, hb, W2cat, b2, (float*)d_out, N);
}

// Round 6
// 345.436 us; speedup vs baseline: 18.6801x; 1.0039x over previous
//
#include <hip/hip_runtime.h>
#include <hip/hip_bf16.h>
#include <math.h>

// N = 100000, E = 1600000, F_IN = H = 128, C = 40
typedef __bf16 bf16x8 __attribute__((ext_vector_type(8)));
typedef float f32x4 __attribute__((ext_vector_type(4)));
typedef unsigned int uint32;

#define FILL_RANGES 16
#define FILL_CHUNK  4096

__device__ __forceinline__ float bflo(uint32 u) { return __uint_as_float(u << 16); }
__device__ __forceinline__ float bfhi(uint32 u) { return __uint_as_float(u & 0xffff0000u); }
__device__ __forceinline__ unsigned short tobf(float f) {
    return __builtin_bit_cast(unsigned short, __float2bfloat16(f));
}

// ---------------- CSR build ----------------

// 4 edges/thread: int4 dst load, 4 independent returning atomics, int4 rank store
__global__ __launch_bounds__(256) void hist_rank_kernel(
    const int* __restrict__ dst, int* __restrict__ cnt,
    int* __restrict__ rank, int nE)
{
    int base = (blockIdx.x * 256 + threadIdx.x) * 4;
    if (base + 4 <= nE) {
        int4 d = *(const int4*)(dst + base);
        int r0 = atomicAdd(&cnt[d.x], 1);
        int r1 = atomicAdd(&cnt[d.y], 1);
        int r2 = atomicAdd(&cnt[d.z], 1);
        int r3 = atomicAdd(&cnt[d.w], 1);
        *(int4*)(rank + base) = make_int4(r0, r1, r2, r3);
    } else {
        for (int e = base; e < nE; ++e)
            rank[e] = atomicAdd(&cnt[dst[e]], 1);
    }
}

// phase 1: per-block (1024 elements) sums
__global__ __launch_bounds__(256) void csr_partial_kernel(
    const int* __restrict__ cnt, int* __restrict__ blocksum, int nN)
{
    int b = blockIdx.x, t = threadIdx.x;
    int base = b * 1024 + t * 4;
    int s = 0;
    #pragma unroll
    for (int k = 0; k < 4; ++k) { int i = base + k; if (i < nN) s += cnt[i]; }
    #pragma unroll
    for (int off = 1; off < 64; off <<= 1) s += __shfl_xor(s, off);
    __shared__ int ws[4];
    int lane = t & 63, w = t >> 6;
    if (lane == 0) ws[w] = s;
    __syncthreads();
    if (t == 0) blocksum[b] = ws[0] + ws[1] + ws[2] + ws[3];
}

// phase 2: scan block sums (<=1024); writes rowptr[nN] = total
__global__ __launch_bounds__(1024) void csr_scanblocks_kernel(
    const int* __restrict__ blocksum, int* __restrict__ blockpre,
    int nB, int* __restrict__ rowptr, int nN)
{
    __shared__ int sm[1024];
    int t = threadIdx.x;
    int v = (t < nB) ? blocksum[t] : 0;
    sm[t] = v;
    __syncthreads();
    for (int off = 1; off < 1024; off <<= 1) {
        int u = (t >= off) ? sm[t - off] : 0;
        __syncthreads();
        sm[t] += u;
        __syncthreads();
    }
    if (t < nB) blockpre[t] = sm[t] - v;
    if (t == 1023) rowptr[nN] = sm[1023];
}

// phase 3: per-block exclusive scan + global offset -> rowptr
__global__ __launch_bounds__(256) void csr_scanfinal_kernel(
    const int* __restrict__ cnt, const int* __restrict__ blockpre,
    int* __restrict__ rowptr, int nN)
{
    int b = blockIdx.x, t = threadIdx.x;
    int base = b * 1024 + t * 4;
    int c[4]; int s = 0;
    #pragma unroll
    for (int k = 0; k < 4; ++k) { int i = base + k; c[k] = (i < nN) ? cnt[i] : 0; s += c[k]; }
    int lane = t & 63, w = t >> 6;
    int inc = s;
    #pragma unroll
    for (int off = 1; off < 64; off <<= 1) {
        int u = __shfl_up(inc, off);
        if (lane >= off) inc += u;
    }
    __shared__ int ws[4];
    if (lane == 63) ws[w] = inc;
    __syncthreads();
    int wpre = 0;
    for (int i = 0; i < w; ++i) wpre += ws[i];
    int run = blockpre[b] + wpre + (inc - s);
    #pragma unroll
    for (int k = 0; k < 4; ++k) {
        int i = base + k;
        if (i < nN) { rowptr[i] = run; run += c[k]; }
    }
}

// range-partitioned, atomic-free fill (scatter window ~L2-resident)
__global__ __launch_bounds__(256) void fill_ranged_kernel(
    const int* __restrict__ src, const int* __restrict__ dst,
    const int* __restrict__ rowptr, const int* __restrict__ rank,
    int* __restrict__ sorted_src, int nE, int nN, int nChunks, int rangeSz)
{
    int range = blockIdx.x / nChunks;
    int chunk = blockIdx.x - range * nChunks;
    int lo = range * rangeSz;
    int hi = lo + rangeSz;
    int e1 = chunk * FILL_CHUNK + FILL_CHUNK; if (e1 > nE) e1 = nE;
    for (int e = chunk * FILL_CHUNK + threadIdx.x; e < e1; e += 256) {
        int d = dst[e];
        if (d >= lo && d < hi && (unsigned)d < (unsigned)nN)
            sorted_src[rowptr[d] + rank[e]] = src[e];
    }
}

// ---------------- conversions ----------------

__global__ __launch_bounds__(256) void cvt_bf16_kernel(
    const float4* __restrict__ in, ushort4* __restrict__ out, int n4)
{
    int i = blockIdx.x * blockDim.x + threadIdx.x;
    int stride = gridDim.x * blockDim.x;
    for (; i < n4; i += stride) {
        float4 v = in[i];
        ushort4 o;
        o.x = tobf(v.x); o.y = tobf(v.y); o.z = tobf(v.z); o.w = tobf(v.w);
        out[i] = o;
    }
}

// W1relB[128*128], W1rootB[128*128], Wpq[128*128]
// Wpq rows: 0..39 = W2_rel, 64..103 = W2_root, rest 0
__global__ __launch_bounds__(256) void prep_weights_kernel(
    const float* __restrict__ W1_rel, const float* __restrict__ W1_root,
    const float* __restrict__ W2_rel, const float* __restrict__ W2_root,
    unsigned short* __restrict__ W1relB, unsigned short* __restrict__ W1rootB,
    unsigned short* __restrict__ Wpq)
{
    int i = blockIdx.x * 256 + threadIdx.x;
    if (i < 16384) {
        W1relB[i] = tobf(W1_rel[i]);
    } else if (i < 32768) {
        int j = i - 16384;
        W1rootB[j] = tobf(W1_root[j]);
    } else if (i < 49152) {
        int j = i - 32768;
        int o = j >> 7, k = j & 127;
        float v = 0.f;
        if (o < 40) v = W2_rel[o * 128 + k];
        else if (o >= 64 && o < 104) v = W2_root[(o - 64) * 128 + k];
        Wpq[j] = tobf(v);
    }
}

// ---------------- layer-1 gather aggregation ----------------
// wave = 1 node, 2 edges in flight (half-wave each), uint2 (4 bf16) per lane
__global__ __launch_bounds__(256) void aggregate_bf16_kernel(
    const uint2* __restrict__ xin2,       // [N][32]
    const int* __restrict__ rowptr,
    const int* __restrict__ sorted_src,
    uint2* __restrict__ aggout2,          // [N][32]
    int nN)
{
    int wave = threadIdx.x >> 6;
    int lane = threadIdx.x & 63;
    int node = blockIdx.x * 4 + wave;
    if (node >= nN) return;
    int half = lane >> 5, l32 = lane & 31;
    int beg = rowptr[node], end = rowptr[node + 1];
    float a0 = 0.f, a1 = 0.f, a2 = 0.f, a3 = 0.f;
    int j = beg;
    for (; j + 4 <= end; j += 4) {
        int s0 = sorted_src[j + half];
        int s1 = sorted_src[j + 2 + half];
        uint2 u0 = xin2[(size_t)s0 * 32 + l32];
        uint2 u1 = xin2[(size_t)s1 * 32 + l32];
        a0 += bflo(u0.x); a1 += bfhi(u0.x); a2 += bflo(u0.y); a3 += bfhi(u0.y);
        a0 += bflo(u1.x); a1 += bfhi(u1.x); a2 += bflo(u1.y); a3 += bfhi(u1.y);
    }
    for (; j + 2 <= end; j += 2) {
        int s = sorted_src[j + half];
        uint2 u = xin2[(size_t)s * 32 + l32];
        a0 += bflo(u.x); a1 += bfhi(u.x); a2 += bflo(u.y); a3 += bfhi(u.y);
    }
    if (j < end && half == 0) {
        int s = sorted_src[j];
        uint2 u = xin2[(size_t)s * 32 + l32];
        a0 += bflo(u.x); a1 += bfhi(u.x); a2 += bflo(u.y); a3 += bfhi(u.y);
    }
    a0 += __shfl_xor(a0, 32);
    a1 += __shfl_xor(a1, 32);
    a2 += __shfl_xor(a2, 32);
    a3 += __shfl_xor(a3, 32);
    if (half == 0) {
        uint2 o;
        o.x = (uint32)tobf(a0) | ((uint32)tobf(a1) << 16);
        o.y = (uint32)tobf(a2) | ((uint32)tobf(a3) << 16);
        aggout2[(size_t)node * 32 + l32] = o;
    }
}

// ---------------- layer 1 GEMM: h = relu([agg|x] @ [W1rel|W1root]^T + b1) ----------------

__global__ __launch_bounds__(256) void gemm1_kernel(
    const unsigned short* __restrict__ aggb,
    const unsigned short* __restrict__ xb,
    const unsigned short* __restrict__ Wrel,
    const unsigned short* __restrict__ Wroot,
    const float* __restrict__ b1,
    unsigned short* __restrict__ hb,
    int nN)
{
    __shared__ __align__(16) unsigned char lds[32768];
    int tid = threadIdx.x;
    int wave = tid >> 6, lane = tid & 63;
    int i0 = blockIdx.x * 64 + wave * 16;
    int mrow = lane & 15, kslot = lane >> 4;
    int arow = i0 + mrow; if (arow >= nN) arow = 0;

    f32x4 acc[8] = {};
    const unsigned short* Asrc[2] = {aggb, xb};
    const unsigned short* Wsrc[2] = {Wrel, Wroot};

    for (int ph = 0; ph < 2; ++ph) {
        __syncthreads();
        const uint4* src = (const uint4*)Wsrc[ph];
        for (int c = tid; c < 2048; c += 256) {
            int row = c >> 4;
            int off = (c & 15) << 4;
            *(uint4*)(&lds[row * 256 + (off ^ ((row & 7) << 4))]) = src[c];
        }
        __syncthreads();
        const unsigned short* Ap = Asrc[ph] + (size_t)arow * 128 + kslot * 8;
        #pragma unroll
        for (int t = 0; t < 4; ++t) {
            bf16x8 a = *(const bf16x8*)(Ap + t * 32);
            #pragma unroll
            for (int ct = 0; ct < 8; ++ct) {
                int o = ct * 16 + mrow;
                int off = (t * 64 + kslot * 16) ^ ((o & 7) << 4);
                bf16x8 b = *(const bf16x8*)(&lds[o * 256 + off]);
                acc[ct] = __builtin_amdgcn_mfma_f32_16x16x32_bf16(a, b, acc[ct], 0, 0, 0);
            }
        }
    }
    #pragma unroll
    for (int ct = 0; ct < 8; ++ct) {
        int col = ct * 16 + mrow;
        float bias = b1[col];
        #pragma unroll
        for (int r = 0; r < 4; ++r) {
            int row = i0 + kslot * 4 + r;
            if (row < nN)
                hb[(size_t)row * 128 + col] = tobf(fmaxf(acc[ct][r] + bias, 0.f));
        }
    }
}

// ---------------- pq = h @ Wpq^T  (p = cols 0..63, q = cols 64..127) ----------------

__global__ __launch_bounds__(256) void gemm_pq_kernel(
    const unsigned short* __restrict__ hb,
    const unsigned short* __restrict__ Wpq,
    unsigned short* __restrict__ pq,
    int nN)
{
    __shared__ __align__(16) unsigned char lds[32768];
    int tid = threadIdx.x;
    int wave = tid >> 6, lane = tid & 63;
    int i0 = blockIdx.x * 64 + wave * 16;
    int mrow = lane & 15, kslot = lane >> 4;
    int arow = i0 + mrow; if (arow >= nN) arow = 0;

    const uint4* src = (const uint4*)Wpq;
    for (int c = tid; c < 2048; c += 256) {
        int row = c >> 4;
        int off = (c & 15) << 4;
        *(uint4*)(&lds[row * 256 + (off ^ ((row & 7) << 4))]) = src[c];
    }
    __syncthreads();

    f32x4 acc[8] = {};
    const unsigned short* Ap = hb + (size_t)arow * 128 + kslot * 8;
    #pragma unroll
    for (int t = 0; t < 4; ++t) {
        bf16x8 a = *(const bf16x8*)(Ap + t * 32);
        #pragma unroll
        for (int ct = 0; ct < 8; ++ct) {
            int o = ct * 16 + mrow;
            int off = (t * 64 + kslot * 16) ^ ((o & 7) << 4);
            bf16x8 b = *(const bf16x8*)(&lds[o * 256 + off]);
            acc[ct] = __builtin_amdgcn_mfma_f32_16x16x32_bf16(a, b, acc[ct], 0, 0, 0);
        }
    }
    #pragma unroll
    for (int ct = 0; ct < 8; ++ct) {
        int col = ct * 16 + mrow;
        #pragma unroll
        for (int r = 0; r < 4; ++r) {
            int row = i0 + kslot * 4 + r;
            if (row < nN)
                pq[(size_t)row * 128 + col] = tobf(acc[ct][r]);
        }
    }
}

// ---------------- final: out = lsm(gather-sum p[neighbors] + q[node] + b2) ----------------
// wave = 1 node; gathers only the p half (128 B/edge); q + bias + log-softmax fused
__global__ __launch_bounds__(256) void final_lsm_kernel(
    const uint32* __restrict__ pqu,       // [N][64] uints; p = 0..31, q = 32..63
    const int* __restrict__ rowptr,
    const int* __restrict__ sorted_src,
    const float* __restrict__ b2,
    float* __restrict__ out,
    int nN)
{
    int wave = threadIdx.x >> 6;
    int lane = threadIdx.x & 63;
    int node = blockIdx.x * 4 + wave;
    if (node >= nN) return;
    int half = lane >> 5, l32 = lane & 31;
    int beg = rowptr[node], end = rowptr[node + 1];

    float a0 = 0.f, a1 = 0.f;
    int j = beg;
    for (; j + 4 <= end; j += 4) {
        int s0 = sorted_src[j + half];
        int s1 = sorted_src[j + 2 + half];
        uint32 u0 = pqu[(size_t)s0 * 64 + l32];
        uint32 u1 = pqu[(size_t)s1 * 64 + l32];
        a0 += bflo(u0); a1 += bfhi(u0);
        a0 += bflo(u1); a1 += bfhi(u1);
    }
    for (; j + 2 <= end; j += 2) {
        int s = sorted_src[j + half];
        uint32 u = pqu[(size_t)s * 64 + l32];
        a0 += bflo(u); a1 += bfhi(u);
    }
    if (j < end && half == 0) {
        uint32 u = pqu[(size_t)sorted_src[j] * 64 + l32];
        a0 += bflo(u); a1 += bfhi(u);
    }
    a0 += __shfl_xor(a0, 32);
    a1 += __shfl_xor(a1, 32);

    // q + bias
    uint32 uq = pqu[(size_t)node * 64 + 32 + l32];
    int c0 = 2 * l32, c1 = c0 + 1;
    float v0 = (c0 < 40) ? (a0 + bflo(uq) + b2[c0]) : -INFINITY;
    float v1 = (c1 < 40) ? (a1 + bfhi(uq) + b2[c1]) : -INFINITY;

    float m = fmaxf(v0, v1);
    #pragma unroll
    for (int off = 16; off >= 1; off >>= 1) m = fmaxf(m, __shfl_xor(m, off));
    float s = ((c0 < 40) ? expf(v0 - m) : 0.f) + ((c1 < 40) ? expf(v1 - m) : 0.f);
    #pragma unroll
    for (int off = 16; off >= 1; off >>= 1) s += __shfl_xor(s, off);
    float lse = m + logf(s);

    if (half == 0 && l32 < 20) {
        float2 o = make_float2(v0 - lse, v1 - lse);
        *(float2*)(out + (size_t)node * 40 + c0) = o;
    }
}

// ---------------- launch ----------------

extern "C" void kernel_launch(void* const* d_in, const int* in_sizes, int n_in,
                              void* d_out, int out_size, void* d_ws, size_t ws_size,
                              hipStream_t stream)
{
    const float* x       = (const float*)d_in[0];
    const int*   ei      = (const int*)d_in[1];
    const float* W1_rel  = (const float*)d_in[2];
    const float* b1      = (const float*)d_in[3];
    const float* W1_root = (const float*)d_in[4];
    const float* W2_rel  = (const float*)d_in[5];
    const float* b2      = (const float*)d_in[6];
    const float* W2_root = (const float*)d_in[7];

    int N = in_sizes[0] / 128;
    int E = in_sizes[1] / 2;
    const int* srcp = ei;
    const int* dstp = ei + E;

    int nB = (N + 1023) / 1024;

    size_t nf = (size_t)N * 128;
    unsigned short* xb      = (unsigned short*)d_ws;   // [N][128] bf16
    unsigned short* aggb    = xb + nf;                 // [N][128]; reused as pq
    unsigned short* hb      = aggb + nf;               // [N][128]
    unsigned short* W1relB  = hb + nf;                 // 16384
    unsigned short* W1rootB = W1relB + 16384;          // 16384
    unsigned short* Wpq     = W1rootB + 16384;         // 16384
    int* rowptr     = (int*)(Wpq + 16384);             // [N+1]
    int* cnt        = rowptr + (N + 1);                // [N]
    int* blocksum   = cnt + N;                         // [nB]
    int* blockpre   = blocksum + nB;                   // [nB]
    int* rank       = blockpre + nB;                   // [E]
    int* sorted_src = rank + E;                        // [E]

    unsigned short* pq = aggb;  // aggb is dead after gemm1

    size_t needed = 3 * nf * sizeof(unsigned short)
                  + (size_t)(3 * 16384) * sizeof(unsigned short)
                  + (size_t)(2 * N + 1 + 2 * nB + 2 * (size_t)E) * sizeof(int);
    if (ws_size < needed) return;

    // CSR build (by destination)
    hipMemsetAsync(cnt, 0, (size_t)N * sizeof(int), stream);
    hist_rank_kernel<<<(E / 4 + 255) / 256, 256, 0, stream>>>(dstp, cnt, rank, E);
    csr_partial_kernel<<<nB, 256, 0, stream>>>(cnt, blocksum, N);
    csr_scanblocks_kernel<<<1, 1024, 0, stream>>>(blocksum, blockpre, nB, rowptr, N);
    csr_scanfinal_kernel<<<nB, 256, 0, stream>>>(cnt, blockpre, rowptr, N);
    {
        int nChunks = (E + FILL_CHUNK - 1) / FILL_CHUNK;
        int rangeSz = (N + FILL_RANGES - 1) / FILL_RANGES;
        fill_ranged_kernel<<<nChunks * FILL_RANGES, 256, 0, stream>>>(
            srcp, dstp, rowptr, rank, sorted_src, E, N, nChunks, rangeSz);
    }

    // conversions
    cvt_bf16_kernel<<<2048, 256, 0, stream>>>((const float4*)x, (ushort4*)xb, (int)(nf / 4));
    prep_weights_kernel<<<192, 256, 0, stream>>>(
        W1_rel, W1_root, W2_rel, W2_root, W1relB, W1rootB, Wpq);

    // layer 1
    aggregate_bf16_kernel<<<(N + 3) / 4, 256, 0, stream>>>(
        (const uint2*)xb, rowptr, sorted_src, (uint2*)aggb, N);
    gemm1_kernel<<<(N + 63) / 64, 256, 0, stream>>>(
        aggb, xb, W1relB, W1rootB, b1, hb, N);

    // layer 2: pre-transform, then fused gather + log-softmax
    gemm_pq_kernel<<<(N + 63) / 64, 256, 0, stream>>>(hb, Wpq, pq, N);
    final_lsm_kernel<<<(N + 3) / 4, 256, 0, stream>>>(
        (const uint32*)pq, rowptr, sorted_src, b2, (float*)d_out, N);
}

// Round 7
// 341.829 us; speedup vs baseline: 18.8772x; 1.0106x over previous
//
#include <hip/hip_runtime.h>
#include <hip/hip_bf16.h>
#include <math.h>

// N = 100000, E = 1600000, F_IN = H = 128, C = 40
typedef __bf16 bf16x8 __attribute__((ext_vector_type(8)));
typedef float f32x4 __attribute__((ext_vector_type(4)));
typedef unsigned int uint32;

#define FILL_RANGES 16
#define FILL_CHUNK  4096
#define NREP 8            // counter replicas (contention reduction)

__device__ __forceinline__ float bflo(uint32 u) { return __uint_as_float(u << 16); }
__device__ __forceinline__ float bfhi(uint32 u) { return __uint_as_float(u & 0xffff0000u); }
__device__ __forceinline__ unsigned short tobf(float f) {
    return __builtin_bit_cast(unsigned short, __float2bfloat16(f));
}

// ---------------- CSR build ----------------

// 2 edges/thread; atomic into replica r = (e>>10)&7 -> ~8x less per-address contention
__global__ __launch_bounds__(256) void hist_rank_kernel(
    const int* __restrict__ dst, int* __restrict__ cnt8,
    int* __restrict__ rank, int nE, int nN)
{
    int base = (blockIdx.x * 256 + threadIdx.x) * 2;
    if (base + 2 <= nE) {
        int2 d2 = *(const int2*)(dst + base);
        int r = (base >> 10) & (NREP - 1);     // same for both edges (base even)
        int* c = cnt8 + (size_t)r * nN;
        int r0 = atomicAdd(&c[d2.x], 1);
        int r1 = atomicAdd(&c[d2.y], 1);
        *(int2*)(rank + base) = make_int2(r0, r1);
    } else {
        for (int e = base; e < nE; ++e) {
            int r = (e >> 10) & (NREP - 1);
            rank[e] = atomicAdd(&cnt8[(size_t)r * nN + dst[e]], 1);
        }
    }
}

// exclusive-scan the 8 replicas per node (in place) and emit total cnt[d]
__global__ __launch_bounds__(256) void combine_kernel(
    int* __restrict__ cnt8, int* __restrict__ cnt, int nN)
{
    int i = blockIdx.x * 256 + threadIdx.x;
    if (i >= nN) return;
    int s = 0;
    #pragma unroll
    for (int r = 0; r < NREP; ++r) {
        size_t idx = (size_t)r * nN + i;
        int c = cnt8[idx];
        cnt8[idx] = s;       // off8[r][i]
        s += c;
    }
    cnt[i] = s;
}

// phase 1: per-block (1024 elements) sums
__global__ __launch_bounds__(256) void csr_partial_kernel(
    const int* __restrict__ cnt, int* __restrict__ blocksum, int nN)
{
    int b = blockIdx.x, t = threadIdx.x;
    int base = b * 1024 + t * 4;
    int s = 0;
    #pragma unroll
    for (int k = 0; k < 4; ++k) { int i = base + k; if (i < nN) s += cnt[i]; }
    #pragma unroll
    for (int off = 1; off < 64; off <<= 1) s += __shfl_xor(s, off);
    __shared__ int ws[4];
    int lane = t & 63, w = t >> 6;
    if (lane == 0) ws[w] = s;
    __syncthreads();
    if (t == 0) blocksum[b] = ws[0] + ws[1] + ws[2] + ws[3];
}

// phase 2: scan block sums (<=1024); writes rowptr[nN] = total
__global__ __launch_bounds__(1024) void csr_scanblocks_kernel(
    const int* __restrict__ blocksum, int* __restrict__ blockpre,
    int nB, int* __restrict__ rowptr, int nN)
{
    __shared__ int sm[1024];
    int t = threadIdx.x;
    int v = (t < nB) ? blocksum[t] : 0;
    sm[t] = v;
    __syncthreads();
    for (int off = 1; off < 1024; off <<= 1) {
        int u = (t >= off) ? sm[t - off] : 0;
        __syncthreads();
        sm[t] += u;
        __syncthreads();
    }
    if (t < nB) blockpre[t] = sm[t] - v;
    if (t == 1023) rowptr[nN] = sm[1023];
}

// phase 3: per-block exclusive scan + global offset -> rowptr
__global__ __launch_bounds__(256) void csr_scanfinal_kernel(
    const int* __restrict__ cnt, const int* __restrict__ blockpre,
    int* __restrict__ rowptr, int nN)
{
    int b = blockIdx.x, t = threadIdx.x;
    int base = b * 1024 + t * 4;
    int c[4]; int s = 0;
    #pragma unroll
    for (int k = 0; k < 4; ++k) { int i = base + k; c[k] = (i < nN) ? cnt[i] : 0; s += c[k]; }
    int lane = t & 63, w = t >> 6;
    int inc = s;
    #pragma unroll
    for (int off = 1; off < 64; off <<= 1) {
        int u = __shfl_up(inc, off);
        if (lane >= off) inc += u;
    }
    __shared__ int ws[4];
    if (lane == 63) ws[w] = inc;
    __syncthreads();
    int wpre = 0;
    for (int i = 0; i < w; ++i) wpre += ws[i];
    int run = blockpre[b] + wpre + (inc - s);
    #pragma unroll
    for (int k = 0; k < 4; ++k) {
        int i = base + k;
        if (i < nN) { rowptr[i] = run; run += c[k]; }
    }
}

// range-partitioned, atomic-free fill (scatter window ~L2-resident)
__global__ __launch_bounds__(256) void fill_ranged_kernel(
    const int* __restrict__ src, const int* __restrict__ dst,
    const int* __restrict__ rowptr, const int* __restrict__ rank,
    const int* __restrict__ cnt8,        // off8[r][d] after combine
    int* __restrict__ sorted_src, int nE, int nN, int nChunks, int rangeSz)
{
    int range = blockIdx.x / nChunks;
    int chunk = blockIdx.x - range * nChunks;
    int lo = range * rangeSz;
    int hi = lo + rangeSz;
    int e1 = chunk * FILL_CHUNK + FILL_CHUNK; if (e1 > nE) e1 = nE;
    for (int e = chunk * FILL_CHUNK + threadIdx.x; e < e1; e += 256) {
        int d = dst[e];
        if (d >= lo && d < hi) {
            int r = (e >> 10) & (NREP - 1);
            sorted_src[rowptr[d] + cnt8[(size_t)r * nN + d] + rank[e]] = src[e];
        }
    }
}

// ---------------- conversions ----------------

__global__ __launch_bounds__(256) void cvt_bf16_kernel(
    const float4* __restrict__ in, ushort4* __restrict__ out, int n4)
{
    int i = blockIdx.x * blockDim.x + threadIdx.x;
    int stride = gridDim.x * blockDim.x;
    for (; i < n4; i += stride) {
        float4 v = in[i];
        ushort4 o;
        o.x = tobf(v.x); o.y = tobf(v.y); o.z = tobf(v.z); o.w = tobf(v.w);
        out[i] = o;
    }
}

// W1relB[128*128], W1rootB[128*128], Wpq[128*128]
// Wpq rows: 0..39 = W2_rel, 64..103 = W2_root, rest 0
__global__ __launch_bounds__(256) void prep_weights_kernel(
    const float* __restrict__ W1_rel, const float* __restrict__ W1_root,
    const float* __restrict__ W2_rel, const float* __restrict__ W2_root,
    unsigned short* __restrict__ W1relB, unsigned short* __restrict__ W1rootB,
    unsigned short* __restrict__ Wpq)
{
    int i = blockIdx.x * 256 + threadIdx.x;
    if (i < 16384) {
        W1relB[i] = tobf(W1_rel[i]);
    } else if (i < 32768) {
        int j = i - 16384;
        W1rootB[j] = tobf(W1_root[j]);
    } else if (i < 49152) {
        int j = i - 32768;
        int o = j >> 7, k = j & 127;
        float v = 0.f;
        if (o < 40) v = W2_rel[o * 128 + k];
        else if (o >= 64 && o < 104) v = W2_root[(o - 64) * 128 + k];
        Wpq[j] = tobf(v);
    }
}

// ---------------- layer-1 gather aggregation ----------------
// wave = 1 node, 2 edges in flight (half-wave each), uint2 (4 bf16) per lane
__global__ __launch_bounds__(256) void aggregate_bf16_kernel(
    const uint2* __restrict__ xin2,       // [N][32]
    const int* __restrict__ rowptr,
    const int* __restrict__ sorted_src,
    uint2* __restrict__ aggout2,          // [N][32]
    int nN)
{
    int wave = threadIdx.x >> 6;
    int lane = threadIdx.x & 63;
    int node = blockIdx.x * 4 + wave;
    if (node >= nN) return;
    int half = lane >> 5, l32 = lane & 31;
    int beg = rowptr[node], end = rowptr[node + 1];
    float a0 = 0.f, a1 = 0.f, a2 = 0.f, a3 = 0.f;
    int j = beg;
    for (; j + 4 <= end; j += 4) {
        int s0 = sorted_src[j + half];
        int s1 = sorted_src[j + 2 + half];
        uint2 u0 = xin2[(size_t)s0 * 32 + l32];
        uint2 u1 = xin2[(size_t)s1 * 32 + l32];
        a0 += bflo(u0.x); a1 += bfhi(u0.x); a2 += bflo(u0.y); a3 += bfhi(u0.y);
        a0 += bflo(u1.x); a1 += bfhi(u1.x); a2 += bflo(u1.y); a3 += bfhi(u1.y);
    }
    for (; j + 2 <= end; j += 2) {
        int s = sorted_src[j + half];
        uint2 u = xin2[(size_t)s * 32 + l32];
        a0 += bflo(u.x); a1 += bfhi(u.x); a2 += bflo(u.y); a3 += bfhi(u.y);
    }
    if (j < end && half == 0) {
        int s = sorted_src[j];
        uint2 u = xin2[(size_t)s * 32 + l32];
        a0 += bflo(u.x); a1 += bfhi(u.x); a2 += bflo(u.y); a3 += bfhi(u.y);
    }
    a0 += __shfl_xor(a0, 32);
    a1 += __shfl_xor(a1, 32);
    a2 += __shfl_xor(a2, 32);
    a3 += __shfl_xor(a3, 32);
    if (half == 0) {
        uint2 o;
        o.x = (uint32)tobf(a0) | ((uint32)tobf(a1) << 16);
        o.y = (uint32)tobf(a2) | ((uint32)tobf(a3) << 16);
        aggout2[(size_t)node * 32 + l32] = o;
    }
}

// ---------------- layer 1 GEMM: h = relu([agg|x] @ [W1rel|W1root]^T + b1) ----------------

__global__ __launch_bounds__(256) void gemm1_kernel(
    const unsigned short* __restrict__ aggb,
    const unsigned short* __restrict__ xb,
    const unsigned short* __restrict__ Wrel,
    const unsigned short* __restrict__ Wroot,
    const float* __restrict__ b1,
    unsigned short* __restrict__ hb,
    int nN)
{
    __shared__ __align__(16) unsigned char lds[32768];
    int tid = threadIdx.x;
    int wave = tid >> 6, lane = tid & 63;
    int i0 = blockIdx.x * 64 + wave * 16;
    int mrow = lane & 15, kslot = lane >> 4;
    int arow = i0 + mrow; if (arow >= nN) arow = 0;

    f32x4 acc[8] = {};
    const unsigned short* Asrc[2] = {aggb, xb};
    const unsigned short* Wsrc[2] = {Wrel, Wroot};

    for (int ph = 0; ph < 2; ++ph) {
        __syncthreads();
        const uint4* src = (const uint4*)Wsrc[ph];
        for (int c = tid; c < 2048; c += 256) {
            int row = c >> 4;
            int off = (c & 15) << 4;
            *(uint4*)(&lds[row * 256 + (off ^ ((row & 7) << 4))]) = src[c];
        }
        __syncthreads();
        const unsigned short* Ap = Asrc[ph] + (size_t)arow * 128 + kslot * 8;
        #pragma unroll
        for (int t = 0; t < 4; ++t) {
            bf16x8 a = *(const bf16x8*)(Ap + t * 32);
            #pragma unroll
            for (int ct = 0; ct < 8; ++ct) {
                int o = ct * 16 + mrow;
                int off = (t * 64 + kslot * 16) ^ ((o & 7) << 4);
                bf16x8 b = *(const bf16x8*)(&lds[o * 256 + off]);
                acc[ct] = __builtin_amdgcn_mfma_f32_16x16x32_bf16(a, b, acc[ct], 0, 0, 0);
            }
        }
    }
    #pragma unroll
    for (int ct = 0; ct < 8; ++ct) {
        int col = ct * 16 + mrow;
        float bias = b1[col];
        #pragma unroll
        for (int r = 0; r < 4; ++r) {
            int row = i0 + kslot * 4 + r;
            if (row < nN)
                hb[(size_t)row * 128 + col] = tobf(fmaxf(acc[ct][r] + bias, 0.f));
        }
    }
}

// ---------------- pq = h @ Wpq^T  (p = cols 0..63, q = cols 64..127) ----------------

__global__ __launch_bounds__(256) void gemm_pq_kernel(
    const unsigned short* __restrict__ hb,
    const unsigned short* __restrict__ Wpq,
    unsigned short* __restrict__ pq,
    int nN)
{
    __shared__ __align__(16) unsigned char lds[32768];
    int tid = threadIdx.x;
    int wave = tid >> 6, lane = tid & 63;
    int i0 = blockIdx.x * 64 + wave * 16;
    int mrow = lane & 15, kslot = lane >> 4;
    int arow = i0 + mrow; if (arow >= nN) arow = 0;

    const uint4* src = (const uint4*)Wpq;
    for (int c = tid; c < 2048; c += 256) {
        int row = c >> 4;
        int off = (c & 15) << 4;
        *(uint4*)(&lds[row * 256 + (off ^ ((row & 7) << 4))]) = src[c];
    }
    __syncthreads();

    f32x4 acc[8] = {};
    const unsigned short* Ap = hb + (size_t)arow * 128 + kslot * 8;
    #pragma unroll
    for (int t = 0; t < 4; ++t) {
        bf16x8 a = *(const bf16x8*)(Ap + t * 32);
        #pragma unroll
        for (int ct = 0; ct < 8; ++ct) {
            int o = ct * 16 + mrow;
            int off = (t * 64 + kslot * 16) ^ ((o & 7) << 4);
            bf16x8 b = *(const bf16x8*)(&lds[o * 256 + off]);
            acc[ct] = __builtin_amdgcn_mfma_f32_16x16x32_bf16(a, b, acc[ct], 0, 0, 0);
        }
    }
    #pragma unroll
    for (int ct = 0; ct < 8; ++ct) {
        int col = ct * 16 + mrow;
        #pragma unroll
        for (int r = 0; r < 4; ++r) {
            int row = i0 + kslot * 4 + r;
            if (row < nN)
                pq[(size_t)row * 128 + col] = tobf(acc[ct][r]);
        }
    }
}

// ---------------- final: out = lsm(gather-sum p[neighbors] + q[node] + b2) ----------------

__global__ __launch_bounds__(256) void final_lsm_kernel(
    const uint32* __restrict__ pqu,       // [N][64] uints; p = 0..31, q = 32..63
    const int* __restrict__ rowptr,
    const int* __restrict__ sorted_src,
    const float* __restrict__ b2,
    float* __restrict__ out,
    int nN)
{
    int wave = threadIdx.x >> 6;
    int lane = threadIdx.x & 63;
    int node = blockIdx.x * 4 + wave;
    if (node >= nN) return;
    int half = lane >> 5, l32 = lane & 31;
    int beg = rowptr[node], end = rowptr[node + 1];

    float a0 = 0.f, a1 = 0.f;
    int j = beg;
    for (; j + 4 <= end; j += 4) {
        int s0 = sorted_src[j + half];
        int s1 = sorted_src[j + 2 + half];
        uint32 u0 = pqu[(size_t)s0 * 64 + l32];
        uint32 u1 = pqu[(size_t)s1 * 64 + l32];
        a0 += bflo(u0); a1 += bfhi(u0);
        a0 += bflo(u1); a1 += bfhi(u1);
    }
    for (; j + 2 <= end; j += 2) {
        int s = sorted_src[j + half];
        uint32 u = pqu[(size_t)s * 64 + l32];
        a0 += bflo(u); a1 += bfhi(u);
    }
    if (j < end && half == 0) {
        uint32 u = pqu[(size_t)sorted_src[j] * 64 + l32];
        a0 += bflo(u); a1 += bfhi(u);
    }
    a0 += __shfl_xor(a0, 32);
    a1 += __shfl_xor(a1, 32);

    uint32 uq = pqu[(size_t)node * 64 + 32 + l32];
    int c0 = 2 * l32, c1 = c0 + 1;
    float v0 = (c0 < 40) ? (a0 + bflo(uq) + b2[c0]) : -INFINITY;
    float v1 = (c1 < 40) ? (a1 + bfhi(uq) + b2[c1]) : -INFINITY;

    float m = fmaxf(v0, v1);
    #pragma unroll
    for (int off = 16; off >= 1; off >>= 1) m = fmaxf(m, __shfl_xor(m, off));
    float s = ((c0 < 40) ? expf(v0 - m) : 0.f) + ((c1 < 40) ? expf(v1 - m) : 0.f);
    #pragma unroll
    for (int off = 16; off >= 1; off >>= 1) s += __shfl_xor(s, off);
    float lse = m + logf(s);

    if (half == 0 && l32 < 20) {
        float2 o = make_float2(v0 - lse, v1 - lse);
        *(float2*)(out + (size_t)node * 40 + c0) = o;
    }
}

// ---------------- launch ----------------

extern "C" void kernel_launch(void* const* d_in, const int* in_sizes, int n_in,
                              void* d_out, int out_size, void* d_ws, size_t ws_size,
                              hipStream_t stream)
{
    const float* x       = (const float*)d_in[0];
    const int*   ei      = (const int*)d_in[1];
    const float* W1_rel  = (const float*)d_in[2];
    const float* b1      = (const float*)d_in[3];
    const float* W1_root = (const float*)d_in[4];
    const float* W2_rel  = (const float*)d_in[5];
    const float* b2      = (const float*)d_in[6];
    const float* W2_root = (const float*)d_in[7];

    int N = in_sizes[0] / 128;
    int E = in_sizes[1] / 2;
    const int* srcp = ei;
    const int* dstp = ei + E;

    int nB = (N + 1023) / 1024;

    size_t nf = (size_t)N * 128;
    unsigned short* xb      = (unsigned short*)d_ws;   // [N][128] bf16
    unsigned short* aggb    = xb + nf;                 // [N][128]; reused as pq
    unsigned short* hb      = aggb + nf;               // [N][128]
    unsigned short* W1relB  = hb + nf;                 // 16384
    unsigned short* W1rootB = W1relB + 16384;          // 16384
    unsigned short* Wpq     = W1rootB + 16384;         // 16384
    int* rowptr     = (int*)(Wpq + 16384);             // [N+1]
    int* cnt        = rowptr + (N + 1);                // [N]
    int* blocksum   = cnt + N;                         // [nB]
    int* blockpre   = blocksum + nB;                   // [nB]
    int* cnt8       = blockpre + nB;                   // [NREP][N]
    int* rank       = cnt8 + (size_t)NREP * N;         // [E]
    int* sorted_src = rank + E;                        // [E]

    unsigned short* pq = aggb;  // aggb is dead after gemm1

    size_t needed = 3 * nf * sizeof(unsigned short)
                  + (size_t)(3 * 16384) * sizeof(unsigned short)
                  + ((size_t)(2 + NREP) * N + 1 + 2 * nB + 2 * (size_t)E) * sizeof(int);
    if (ws_size < needed) return;

    // CSR build (by destination), replicated counters
    hipMemsetAsync(cnt8, 0, (size_t)NREP * N * sizeof(int), stream);
    hist_rank_kernel<<<(E / 2 + 255) / 256, 256, 0, stream>>>(dstp, cnt8, rank, E, N);
    combine_kernel<<<(N + 255) / 256, 256, 0, stream>>>(cnt8, cnt, N);
    csr_partial_kernel<<<nB, 256, 0, stream>>>(cnt, blocksum, N);
    csr_scanblocks_kernel<<<1, 1024, 0, stream>>>(blocksum, blockpre, nB, rowptr, N);
    csr_scanfinal_kernel<<<nB, 256, 0, stream>>>(cnt, blockpre, rowptr, N);
    {
        int nChunks = (E + FILL_CHUNK - 1) / FILL_CHUNK;
        int rangeSz = (N + FILL_RANGES - 1) / FILL_RANGES;
        fill_ranged_kernel<<<nChunks * FILL_RANGES, 256, 0, stream>>>(
            srcp, dstp, rowptr, rank, cnt8, sorted_src, E, N, nChunks, rangeSz);
    }

    // conversions
    cvt_bf16_kernel<<<2048, 256, 0, stream>>>((const float4*)x, (ushort4*)xb, (int)(nf / 4));
    prep_weights_kernel<<<192, 256, 0, stream>>>(
        W1_rel, W1_root, W2_rel, W2_root, W1relB, W1rootB, Wpq);

    // layer 1
    aggregate_bf16_kernel<<<(N + 3) / 4, 256, 0, stream>>>(
        (const uint2*)xb, rowptr, sorted_src, (uint2*)aggb, N);
    gemm1_kernel<<<(N + 63) / 64, 256, 0, stream>>>(
        aggb, xb, W1relB, W1rootB, b1, hb, N);

    // layer 2: pre-transform, then fused gather + log-softmax
    gemm_pq_kernel<<<(N + 63) / 64, 256, 0, stream>>>(hb, Wpq, pq, N);
    final_lsm_kernel<<<(N + 3) / 4, 256, 0, stream>>>(
        (const uint32*)pq, rowptr, sorted_src, b2, (float*)d_out, N);
}